// Round 12
// baseline (387.018 us; speedup 1.0000x reference)
//
#include <hip/hip_runtime.h>
#include <math.h>

#define T_   256
#define B_   32
#define N_   16
#define F_   128
#define H_   256
#define BN_  512          // B*N
#define G3_  768          // 3*H
#define CL_  16           // chunk length
#define NC_  16           // number of chunks (T_/CL_)

typedef __attribute__((ext_vector_type(8))) short  bf16x8;
typedef __attribute__((ext_vector_type(4))) float  f32x4;
typedef __attribute__((ext_vector_type(4))) unsigned short u16x4;

// ---- workspace layout (bytes) ----
#define OFF_H1   0ULL                        // f32 [NC][BN][H]   8 MB
#define OFF_HIN  8388608ULL                  // f32 [NC][BN][H]   8 MB
#define OFF_WBF  16777216ULL                 // bf16 [768][256]   384 KB
#define OFF_DM   17170432ULL                 // u32 [NC][BN]      32 KB
#define OFF_XG   17203200ULL                 // bf16 xg2 tiled    192 MB
#define WS_NEED  218529792ULL

__device__ __forceinline__ unsigned short f2bf(float f) {   // RNE float->bf16
    union { float f; unsigned u; } v; v.f = f;
    unsigned u = v.u + 0x7FFFu + ((v.u >> 16) & 1u);
    return (unsigned short)(u >> 16);
}
__device__ __forceinline__ float bf2f(unsigned short h) {
    union { unsigned u; float f; } v; v.u = ((unsigned)h) << 16;
    return v.f;
}
__device__ __forceinline__ bf16x8 load_pack8(const float* __restrict__ p) {
    f32x4 a = *(const f32x4*)p;
    f32x4 b = *(const f32x4*)(p + 4);
    bf16x8 r;
    r[0]=(short)f2bf(a[0]); r[1]=(short)f2bf(a[1]); r[2]=(short)f2bf(a[2]); r[3]=(short)f2bf(a[3]);
    r[4]=(short)f2bf(b[0]); r[5]=(short)f2bf(b[1]); r[6]=(short)f2bf(b[2]); r[7]=(short)f2bf(b[3]);
    return r;
}
__device__ __forceinline__ float sigmoidf_(float x) { return 1.0f / (1.0f + __expf(-x)); }
__device__ __forceinline__ float tanhf_(float x)    { return 1.0f - 2.0f / (__expf(2.0f * x) + 1.0f); }

// Pin a bf16x8 fragment to the AGPR class (empty asm; builtin MFMA reads A
// from AGPR directly — AV operand class — with compiler-managed hazards).
__device__ __forceinline__ bf16x8 pin_a(bf16x8 v) {
    bf16x8 r;
    asm("" : "=a"(r) : "0"(v));
    return r;
}

// xg2 tiled layout: u16 index for element (tt, seq, g)
__device__ __forceinline__ size_t xg2_idx(int tt, int seq, int g) {
    return ((((size_t)tt * 32 + (seq >> 4)) * 48 + (g >> 4)) * 64
            + ((g >> 2) & 3) * 16 + (seq & 15)) * 4 + (g & 3);
}

// One GRU step for one chain (proven round-6/11 step body, parameterized).
template<bool WRITE_OUT>
__device__ __forceinline__ void gru_step_phase(
    int t, int cc, unsigned mm, int buf,
    int wave, int lane, int lr, int lg, int jb, int sb, int bn0,
    unsigned short (&hTc)[2][8][4][16][8],
    float (&hpc)[16][260],
    const float* bhnL,
    const bf16x8 (&wfa)[8][8], const bf16x8 (&wfv)[4][8],
    const unsigned short* __restrict__ xg2,
    float* __restrict__ out)
{
    const int tt = cc * CL_ + t;
    const int tb = (tt * 32 + sb) * 48;

    u16x4 xv[3][4];
    #pragma unroll
    for (int g = 0; g < 3; ++g)
        #pragma unroll
        for (int ms = 0; ms < 4; ++ms)
            xv[g][ms] = ((const u16x4*)xg2)[(size_t)(tb + g*16 + wave*4 + ms) * 64 + lane];

    const int d = (mm >> t) & 1;
    const short dms = (short)(d ? 0 : -1);

    f32x4 acc[12];
    #pragma unroll
    for (int mt = 0; mt < 8; ++mt) acc[mt] = (f32x4){0.f, 0.f, 0.f, 0.f};
    #pragma unroll
    for (int ms = 0; ms < 4; ++ms)                 // n-gate seeded with b_hh_n
        acc[8 + ms] = *(const f32x4*)&bhnL[jb + ms*16 + lg*4];

    #pragma unroll
    for (int kt = 0; kt < 8; ++kt) {
        bf16x8 hv = *(const bf16x8*)&hTc[buf][kt][lg][lr][0];
        hv = hv & dms;
        #pragma unroll
        for (int mt = 0; mt < 8; ++mt)
            acc[mt] = __builtin_amdgcn_mfma_f32_16x16x32_bf16(wfa[mt][kt], hv, acc[mt], 0, 0, 0);
        #pragma unroll
        for (int ms = 0; ms < 4; ++ms)
            acc[8 + ms] = __builtin_amdgcn_mfma_f32_16x16x32_bf16(wfv[ms][kt], hv, acc[8 + ms], 0, 0, 0);
    }

    #pragma unroll
    for (int ms = 0; ms < 4; ++ms) {
        const int jq = jb + ms*16 + lg*4;
        f32x4 hp4 = *(const f32x4*)&hpc[lr][jq];
        f32x4 hnew4; u16x4 hb;
        #pragma unroll
        for (int q = 0; q < 4; ++q) {
            float r = sigmoidf_(acc[0 + ms][q] + bf2f(xv[0][ms][q]));
            float z = sigmoidf_(acc[4 + ms][q] + bf2f(xv[1][ms][q]));
            float n = tanhf_(bf2f(xv[2][ms][q]) + r * acc[8 + ms][q]);
            float hpv = d ? 0.0f : hp4[q];
            float hn2 = n + z * (hpv - n);
            hnew4[q] = hn2; hb[q] = f2bf(hn2);
        }
        *(f32x4*)&hpc[lr][jq] = hnew4;
        *(u16x4*)&hTc[buf ^ 1][jq >> 5][(jq >> 3) & 3][lr][jq & 7] = hb;
        if (WRITE_OUT)
            *(f32x4*)(out + ((size_t)tt * BN_ + bn0 + lr) * H_ + jq) = hnew4;
    }
}

// ---------------------------------------------------------------------------
// xg3: pipelined input-projection GEMM (round-11 proven). 256 persistent
// compute blocks (1/CU, 512 thr), double-buffered LDS, loads of tile i+1
// in flight under compute of tile i. Blocks >= 256: fused prep.
// ---------------------------------------------------------------------------
__global__ __launch_bounds__(512, 2)
void xg3_kernel(const float* __restrict__ x, const float* __restrict__ W_ih,
                const float* __restrict__ b_ih, const float* __restrict__ b_hh,
                const float* __restrict__ W_hh, const int* __restrict__ dones,
                unsigned short* __restrict__ xg2,
                unsigned short* __restrict__ wbf, unsigned int* __restrict__ dm)
{
    const int tid = threadIdx.x;
    if (blockIdx.x >= 256) {                        // ---- fused prep ----
        const int bid2 = blockIdx.x - 256;
        if (bid2 < 96) {                            // W_hh f32 -> bf16
            const int i4 = bid2 * 512 + tid;        // 49152 f32x4 units
            f32x4 w = ((const f32x4*)W_hh)[i4];
            u16x4 o;
            #pragma unroll
            for (int q = 0; q < 4; ++q) o[q] = f2bf(w[q]);
            ((u16x4*)wbf)[i4] = o;
        } else {                                    // done masks (u32, CL=16)
            const int u = (bid2 - 96) * 512 + tid;  // 8192 = NC*BN
            const int c = u >> 9, s = u & 511;
            unsigned m = 0;
            #pragma unroll
            for (int k = 0; k < CL_; ++k)
                m |= (dones[(c * CL_ + k) * BN_ + s] ? 1u : 0u) << k;
            dm[c * BN_ + s] = m;
        }
        return;
    }

    __shared__ __align__(16) unsigned short xls[2][128][136];   // 69.6 KB dbuf

    const int wave = tid >> 6, lane = tid & 63;
    const int lr = lane & 15, lg = lane >> 4;
    const int t  = blockIdx.x;                      // one timestep per block
    const int g0 = wave * 96;

    bf16x8 wf[6][4];
    #pragma unroll
    for (int gt = 0; gt < 6; ++gt)
        #pragma unroll
        for (int kt = 0; kt < 4; ++kt)
            wf[gt][kt] = load_pack8(W_ih + (size_t)(g0 + gt*16 + lr) * F_ + kt*32 + lg*8);

    float bv[6][4];
    #pragma unroll
    for (int gt = 0; gt < 6; ++gt)
        #pragma unroll
        for (int q = 0; q < 4; ++q) {
            const int g = g0 + gt*16 + lg*4 + q;
            bv[gt][q] = b_ih[g] + (g < 2*H_ ? b_hh[g] : 0.0f);
        }

    {
        f32x4 sv0[8];
        #pragma unroll
        for (int s = 0; s < 8; ++s)
            sv0[s] = ((const f32x4*)x)[(size_t)t * 16384 + s*512 + tid];
        #pragma unroll
        for (int s = 0; s < 8; ++s) {
            u16x4 o;
            #pragma unroll
            for (int q = 0; q < 4; ++q) o[q] = f2bf(sv0[s][q]);
            const int u = s*512 + tid;
            *(u16x4*)&xls[0][u >> 5][(u & 31) * 4] = o;
        }
    }
    __syncthreads();

    int buf = 0;
    #pragma unroll 1
    for (int i = 0; i < 4; ++i) {
        f32x4 sv[8];
        if (i < 3) {
            #pragma unroll
            for (int s = 0; s < 8; ++s)
                sv[s] = ((const f32x4*)x)[(size_t)t * 16384 + (i+1)*4096 + s*512 + tid];
        }

        #pragma unroll
        for (int tbt = 0; tbt < 8; ++tbt) {
            bf16x8 xf[4];
            #pragma unroll
            for (int kt = 0; kt < 4; ++kt)
                xf[kt] = *(const bf16x8*)&xls[buf][tbt*16 + lr][kt*32 + lg*8];

            f32x4 acc[6];
            #pragma unroll
            for (int gt = 0; gt < 6; ++gt) acc[gt] = (f32x4){0.f, 0.f, 0.f, 0.f};

            #pragma unroll
            for (int kt = 0; kt < 4; ++kt)
                #pragma unroll
                for (int gt = 0; gt < 6; ++gt)
                    acc[gt] = __builtin_amdgcn_mfma_f32_16x16x32_bf16(wf[gt][kt], xf[kt], acc[gt], 0, 0, 0);

            const int sbg = i*8 + tbt;
            #pragma unroll
            for (int gt = 0; gt < 6; ++gt) {
                u16x4 o;
                #pragma unroll
                for (int q = 0; q < 4; ++q) o[q] = f2bf(acc[gt][q] + bv[gt][q]);
                const size_t base = (((size_t)t * 32 + sbg) * 48 + (wave*6 + gt)) * 64 + lane;
                *(u16x4*)(xg2 + base * 4) = o;
            }
        }

        if (i < 3) {
            #pragma unroll
            for (int s = 0; s < 8; ++s) {
                u16x4 o;
                #pragma unroll
                for (int q = 0; q < 4; ++q) o[q] = f2bf(sv[s][q]);
                const int u = s*512 + tid;
                *(u16x4*)&xls[buf ^ 1][u >> 5][(u & 31) * 4] = o;
            }
            __syncthreads();
        }
        buf ^= 1;
    }
}

// ---------------------------------------------------------------------------
// pass1 (chunk-paired): 256 blocks = 8 pairs x 32 groups. Block runs chains
// for chunks {2p, 2p+1} (B skipped when 2p+1 == NC-1: h1[15] unused).
// Weights loaded ONCE, shared by both chains. One barrier per interval.
// ---------------------------------------------------------------------------
__global__ __launch_bounds__(256, 1)
void pass1_kernel(const unsigned short* __restrict__ xg2,
                  const unsigned int*  __restrict__ dm,
                  const unsigned short* __restrict__ wbf,
                  const float* __restrict__ b_hh,
                  float* __restrict__ h1)
{
    __shared__ __align__(16) unsigned short hT[2][2][8][4][16][8];  // 32 KB
    __shared__ __align__(16) float hpL[2][16][260];                 // 33.3 KB
    __shared__ float bhnL[H_];                                      // 1 KB

    const int tid  = threadIdx.x;
    const int wave = tid >> 6, lane = tid & 63;
    const int lr = lane & 15, lg = lane >> 4;
    const int pair = blockIdx.x >> 5;
    const int bn0  = (blockIdx.x & 31) * 16;
    const int jb   = wave * 64;
    const int cA = 2*pair, cB = 2*pair + 1;

    const unsigned mA = dm[cA * BN_ + bn0 + lr];
    bool aAct = (__ballot(mA != 0) != 0ULL);
    unsigned mB = 0;
    bool bAct = false;
    if (cB < NC_ - 1) {
        mB = dm[cB * BN_ + bn0 + lr];
        bAct = (__ballot(mB != 0) != 0ULL);
    }
    if (!aAct && !bAct) return;

    int lastA = mA ? (31 - __builtin_clz(mA)) : (CL_ - 1);
    int lastB = mB ? (31 - __builtin_clz(mB)) : (CL_ - 1);
    #pragma unroll
    for (int w = 1; w < 16; w <<= 1) {
        lastA = min(lastA, __shfl_xor(lastA, w));
        lastB = min(lastB, __shfl_xor(lastB, w));
    }
    const int tmin = min(aAct ? lastA : CL_ - 1, bAct ? lastB : CL_ - 1);

    bhnL[tid] = b_hh[2*H_ + tid];
    // zero both chains' hT (both buffers) + hpL
    #pragma unroll
    for (int u = tid; u < 2048; u += 256)
        ((bf16x8*)hT)[u] = (bf16x8)(short)0;
    #pragma unroll
    for (int u = tid; u < 2048; u += 256) {
        const int ch = u >> 10, rem = u & 1023, seq = rem >> 6, jq4 = rem & 63;
        *(f32x4*)&hpL[ch][seq][jq4 * 4] = (f32x4){0.f, 0.f, 0.f, 0.f};
    }

    bf16x8 wfa[8][8];   // r+z -> AGPR
    bf16x8 wfv[4][8];   // n   -> VGPR
    #pragma unroll
    for (int mt = 0; mt < 8; ++mt) {
        const int row = (mt >> 2) * H_ + jb + (mt & 3) * 16 + lr;
        #pragma unroll
        for (int kt = 0; kt < 8; ++kt)
            wfa[mt][kt] = pin_a(*(const bf16x8*)(wbf + (size_t)row * H_ + kt*32 + lg*8));
    }
    #pragma unroll
    for (int ms = 0; ms < 4; ++ms) {
        const int row = 2 * H_ + jb + ms * 16 + lr;
        #pragma unroll
        for (int kt = 0; kt < 8; ++kt)
            wfv[ms][kt] = *(const bf16x8*)(wbf + (size_t)row * H_ + kt*32 + lg*8);
    }
    __syncthreads();

    const int sb = bn0 >> 4;
    int buf = 0;
    for (int t = tmin; t < CL_; ++t) {
        if (aAct && t >= lastA)
            gru_step_phase<false>(t, cA, mA, buf, wave, lane, lr, lg, jb, sb, bn0,
                                  hT[0], hpL[0], bhnL, wfa, wfv, xg2, (float*)0);
        if (bAct && t >= lastB)
            gru_step_phase<false>(t, cB, mB, buf, wave, lane, lr, lg, jb, sb, bn0,
                                  hT[1], hpL[1], bhnL, wfa, wfv, xg2, (float*)0);
        __syncthreads();
        buf ^= 1;
    }

    if (aAct) {
        #pragma unroll
        for (int ms = 0; ms < 4; ++ms) {
            const int jq = jb + ms*16 + lg*4;
            *(f32x4*)(h1 + ((size_t)cA * BN_ + bn0 + lr) * H_ + jq) = *(const f32x4*)&hpL[0][lr][jq];
        }
    }
    if (bAct) {
        #pragma unroll
        for (int ms = 0; ms < 4; ++ms) {
            const int jq = jb + ms*16 + lg*4;
            *(f32x4*)(h1 + ((size_t)cB * BN_ + bn0 + lr) * H_ + jq) = *(const f32x4*)&hpL[1][lr][jq];
        }
    }
}

// ---------------------------------------------------------------------------
// pass2: chain h across chunks. Copy when chunk has a done; rare VALU GRU.
// ---------------------------------------------------------------------------
__global__ __launch_bounds__(256)
void pass2_kernel(const unsigned short* __restrict__ xg2,
                  const unsigned int*  __restrict__ dm,
                  const unsigned short* __restrict__ wbf,
                  const float* __restrict__ b_hh,
                  const float* __restrict__ h0,
                  const float* __restrict__ h1,
                  float* __restrict__ hin)
{
    __shared__ unsigned short hsb[H_];
    const int s = blockIdx.x, j = threadIdx.x;
    float h = h0[(size_t)s * H_ + j];
    const float bhn = b_hh[2*H_ + j];

    for (int c = 0; c < NC_; ++c) {
        hin[((size_t)c * BN_ + s) * H_ + j] = h;
        if (c == NC_ - 1) break;
        const unsigned m = dm[c * BN_ + s];         // block-uniform
        if (m) {
            h = h1[((size_t)c * BN_ + s) * H_ + j];
        } else {
            for (int t = 0; t < CL_; ++t) {
                hsb[j] = f2bf(h);
                __syncthreads();
                float a0 = 0.f, a1 = 0.f, a2 = 0.f;
                for (int k = 0; k < H_; ++k) {
                    float hk = bf2f(hsb[k]);
                    a0 = fmaf(bf2f(wbf[(size_t)j * H_ + k]),          hk, a0);
                    a1 = fmaf(bf2f(wbf[(size_t)(H_ + j) * H_ + k]),   hk, a1);
                    a2 = fmaf(bf2f(wbf[(size_t)(2*H_ + j) * H_ + k]), hk, a2);
                }
                const int tt = c * CL_ + t;
                float xr = bf2f(xg2[xg2_idx(tt, s, j)]);
                float xz = bf2f(xg2[xg2_idx(tt, s, H_ + j)]);
                float xn = bf2f(xg2[xg2_idx(tt, s, 2*H_ + j)]);
                float r = sigmoidf_(a0 + xr);
                float z = sigmoidf_(a1 + xz);
                float n = tanhf_(xn + r * (a2 + bhn));
                h = n + z * (h - n);
                __syncthreads();
            }
        }
    }
}

// ---------------------------------------------------------------------------
// pass3 (chunk-paired): 256 blocks = 8 pairs x 32 groups. Both chains active;
// 16 barrier intervals, each running two independent chunk steps.
// ---------------------------------------------------------------------------
__global__ __launch_bounds__(256, 1)
void pass3_kernel(const unsigned short* __restrict__ xg2,
                  const unsigned int*  __restrict__ dm,
                  const unsigned short* __restrict__ wbf,
                  const float* __restrict__ b_hh,
                  const float* __restrict__ hin,
                  float* __restrict__ out)
{
    __shared__ __align__(16) unsigned short hT[2][2][8][4][16][8];  // 32 KB
    __shared__ __align__(16) float hpL[2][16][260];                 // 33.3 KB
    __shared__ float bhnL[H_];                                      // 1 KB

    const int tid  = threadIdx.x;
    const int wave = tid >> 6, lane = tid & 63;
    const int lr = lane & 15, lg = lane >> 4;
    const int pair = blockIdx.x >> 5;
    const int bn0  = (blockIdx.x & 31) * 16;
    const int jb   = wave * 64;
    const int cA = 2*pair, cB = 2*pair + 1;

    const unsigned mA = dm[cA * BN_ + bn0 + lr];
    const unsigned mB = dm[cB * BN_ + bn0 + lr];

    bhnL[tid] = b_hh[2*H_ + tid];
    // stage hin for both chains: f32 -> hpL, bf16 -> hT[ch][0]
    #pragma unroll
    for (int ch = 0; ch < 2; ++ch) {
        const int cc = cA + ch;
        #pragma unroll
        for (int sweep = 0; sweep < 4; ++sweep) {
            const int u = sweep * 256 + tid, seq = u >> 6, jq = u & 63;
            f32x4 hv = ((const f32x4*)hin)[((size_t)cc * BN_ + bn0 + seq) * 64 + jq];
            *(f32x4*)&hpL[ch][seq][jq * 4] = hv;
        }
        #pragma unroll
        for (int sweep = 0; sweep < 2; ++sweep) {
            const int u = sweep * 256 + tid, col = u & 15, kb = (u >> 4) * 8;
            bf16x8 hv = load_pack8(hin + ((size_t)cc * BN_ + bn0 + col) * H_ + kb);
            ((bf16x8*)hT)[ch * 1024 + u] = hv;      // chain ch, buf 0
        }
    }

    bf16x8 wfa[8][8];
    bf16x8 wfv[4][8];
    #pragma unroll
    for (int mt = 0; mt < 8; ++mt) {
        const int row = (mt >> 2) * H_ + jb + (mt & 3) * 16 + lr;
        #pragma unroll
        for (int kt = 0; kt < 8; ++kt)
            wfa[mt][kt] = pin_a(*(const bf16x8*)(wbf + (size_t)row * H_ + kt*32 + lg*8));
    }
    #pragma unroll
    for (int ms = 0; ms < 4; ++ms) {
        const int row = 2 * H_ + jb + ms * 16 + lr;
        #pragma unroll
        for (int kt = 0; kt < 8; ++kt)
            wfv[ms][kt] = *(const bf16x8*)(wbf + (size_t)row * H_ + kt*32 + lg*8);
    }
    __syncthreads();

    const int sb = bn0 >> 4;
    int buf = 0;
    for (int t = 0; t < CL_; ++t) {
        gru_step_phase<true>(t, cA, mA, buf, wave, lane, lr, lg, jb, sb, bn0,
                             hT[0], hpL[0], bhnL, wfa, wfv, xg2, out);
        gru_step_phase<true>(t, cB, mB, buf, wave, lane, lr, lg, jb, sb, bn0,
                             hT[1], hpL[1], bhnL, wfa, wfv, xg2, out);
        __syncthreads();
        buf ^= 1;
    }

    if (cB == NC_ - 1) {        // final_h from chain B of the last pair
        #pragma unroll
        for (int ms = 0; ms < 4; ++ms) {
            const int jq = jb + ms*16 + lg*4;
            *(f32x4*)(out + (size_t)T_ * BN_ * H_ + (size_t)(bn0 + lr) * H_ + jq)
                = *(const f32x4*)&hpL[1][lr][jq];
        }
    }
}

// ---------------------------------------------------------------------------
// Fallback (ws too small): fp32 VALU persistent kernel (correct, slow)
// ---------------------------------------------------------------------------
#define SPB 4
__global__ __launch_bounds__(256, 1)
void slotgru_fallback(const float* __restrict__ x, const int* __restrict__ dones,
                      const float* __restrict__ h0, const float* __restrict__ W_ih,
                      const float* __restrict__ W_hh, const float* __restrict__ b_ih,
                      const float* __restrict__ b_hh, float* __restrict__ out)
{
    __shared__ __align__(16) float xs[SPB][F_];
    __shared__ __align__(16) float hs[SPB][H_];
    const int j = threadIdx.x, bn0 = blockIdx.x * SPB;
    const float bi0 = b_ih[j], bi1 = b_ih[H_ + j], bi2 = b_ih[2*H_ + j];
    const float bh0 = b_hh[j], bh1 = b_hh[H_ + j], bh2 = b_hh[2*H_ + j];
    const float4* wi0 = (const float4*)(W_ih + (size_t)j * F_);
    const float4* wi1 = (const float4*)(W_ih + (size_t)(H_ + j) * F_);
    const float4* wi2 = (const float4*)(W_ih + (size_t)(2*H_ + j) * F_);
    const float4* wh0 = (const float4*)(W_hh + (size_t)j * H_);
    const float4* wh1 = (const float4*)(W_hh + (size_t)(H_ + j) * H_);
    const float4* wh2 = (const float4*)(W_hh + (size_t)(2*H_ + j) * H_);
    float hreg[SPB];
    #pragma unroll
    for (int s = 0; s < SPB; ++s) { float h = h0[(size_t)(bn0+s)*H_ + j]; hreg[s]=h; hs[s][j]=h; }
    for (int t = 0; t < T_; ++t) {
        int d[SPB];
        #pragma unroll
        for (int s = 0; s < SPB; ++s) d[s] = dones[(size_t)t*BN_ + bn0 + s];
        const float* xsrc = x + (size_t)((size_t)t*BN_ + bn0) * F_;
        ((float*)xs)[j] = xsrc[j]; ((float*)xs)[j+256] = xsrc[j+256];
        #pragma unroll
        for (int s = 0; s < SPB; ++s) if (d[s]) hs[s][j] = 0.0f;
        __syncthreads();
        float ax0[SPB]={0,0,0,0}, ax1[SPB]={0,0,0,0}, ax2[SPB]={0,0,0,0};
        #pragma unroll 8
        for (int cc = 0; cc < F_/4; ++cc) {
            float4 w0=wi0[cc], w1=wi1[cc], w2=wi2[cc];
            #pragma unroll
            for (int s = 0; s < SPB; ++s) {
                float4 xv = ((const float4*)xs[s])[cc];
                ax0[s]=fmaf(w0.x,xv.x,fmaf(w0.y,xv.y,fmaf(w0.z,xv.z,fmaf(w0.w,xv.w,ax0[s]))));
                ax1[s]=fmaf(w1.x,xv.x,fmaf(w1.y,xv.y,fmaf(w1.z,xv.z,fmaf(w1.w,xv.w,ax1[s]))));
                ax2[s]=fmaf(w2.x,xv.x,fmaf(w2.y,xv.y,fmaf(w2.z,xv.z,fmaf(w2.w,xv.w,ax2[s]))));
            }
        }
        float ah0[SPB]={0,0,0,0}, ah1[SPB]={0,0,0,0}, ah2[SPB]={0,0,0,0};
        if (!(d[0]&&d[1]&&d[2]&&d[3])) {
            #pragma unroll 4
            for (int cc = 0; cc < H_/4; ++cc) {
                float4 w0=wh0[cc], w1=wh1[cc], w2=wh2[cc];
                #pragma unroll
                for (int s = 0; s < SPB; ++s) if (!d[s]) {
                    float4 hv = ((const float4*)hs[s])[cc];
                    ah0[s]=fmaf(w0.x,hv.x,fmaf(w0.y,hv.y,fmaf(w0.z,hv.z,fmaf(w0.w,hv.w,ah0[s]))));
                    ah1[s]=fmaf(w1.x,hv.x,fmaf(w1.y,hv.y,fmaf(w1.z,hv.z,fmaf(w1.w,hv.w,ah1[s]))));
                    ah2[s]=fmaf(w2.x,hv.x,fmaf(w2.y,hv.y,fmaf(w2.z,hv.z,fmaf(w2.w,hv.w,ah2[s]))));
                }
            }
        }
        float hnew[SPB];
        #pragma unroll
        for (int s = 0; s < SPB; ++s) {
            float hpv = d[s] ? 0.0f : hreg[s];
            float r = sigmoidf_(ax0[s] + bi0 + ah0[s] + bh0);
            float z = sigmoidf_(ax1[s] + bi1 + ah1[s] + bh1);
            float n = tanhf_(ax2[s] + bi2 + r * (ah2[s] + bh2));
            hnew[s] = (1.0f - z) * n + z * hpv;
        }
        __syncthreads();
        #pragma unroll
        for (int s = 0; s < SPB; ++s) {
            hs[s][j] = hnew[s]; hreg[s] = hnew[s];
            out[(size_t)((size_t)t*BN_ + bn0 + s) * H_ + j] = hnew[s];
        }
    }
    #pragma unroll
    for (int s = 0; s < SPB; ++s)
        out[(size_t)T_*BN_*H_ + (size_t)(bn0+s)*H_ + j] = hreg[s];
}

extern "C" void kernel_launch(void* const* d_in, const int* in_sizes, int n_in,
                              void* d_out, int out_size, void* d_ws, size_t ws_size,
                              hipStream_t stream) {
    const float* x     = (const float*)d_in[0];
    const int*   dones = (const int*)  d_in[1];
    const float* h0    = (const float*)d_in[2];
    const float* W_ih  = (const float*)d_in[3];
    const float* W_hh  = (const float*)d_in[4];
    const float* b_ih  = (const float*)d_in[5];
    const float* b_hh  = (const float*)d_in[6];
    float*       out   = (float*)d_out;

    if (ws_size >= WS_NEED) {
        char* ws = (char*)d_ws;
        float*          h1  = (float*)(ws + OFF_H1);
        float*          hin = (float*)(ws + OFF_HIN);
        unsigned short* wbf = (unsigned short*)(ws + OFF_WBF);
        unsigned int*   dmm = (unsigned int*)(ws + OFF_DM);
        unsigned short* xg2 = (unsigned short*)(ws + OFF_XG);

        hipLaunchKernelGGL(xg3_kernel, dim3(256 + 112), dim3(512), 0, stream,
                           x, W_ih, b_ih, b_hh, W_hh, dones, xg2, wbf, dmm);
        hipLaunchKernelGGL(pass1_kernel, dim3(256), dim3(256), 0, stream,
                           xg2, dmm, wbf, b_hh, h1);
        hipLaunchKernelGGL(pass2_kernel, dim3(BN_), dim3(256), 0, stream,
                           xg2, dmm, wbf, b_hh, h0, h1, hin);
        hipLaunchKernelGGL(pass3_kernel, dim3(256), dim3(256), 0, stream,
                           xg2, dmm, wbf, b_hh, hin, out);
    } else {
        hipLaunchKernelGGL(slotgru_fallback, dim3(BN_ / SPB), dim3(256), 0, stream,
                           x, dones, h0, W_ih, W_hh, b_ih, b_hh, out);
    }
}

// Round 14
// 334.650 us; speedup vs baseline: 1.1565x; 1.1565x over previous
//
#include <hip/hip_runtime.h>
#include <math.h>

#define T_   256
#define B_   32
#define N_   16
#define F_   128
#define H_   256
#define BN_  512          // B*N
#define G3_  768          // 3*H
#define CL_  32           // chunk length
#define NC_  8            // number of chunks (T_/CL_)

typedef __attribute__((ext_vector_type(8))) short  bf16x8;
typedef __attribute__((ext_vector_type(4))) float  f32x4;
typedef __attribute__((ext_vector_type(4))) unsigned short u16x4;

// ---- workspace layout (bytes) ----  (identical to round 6/11)
#define OFF_H1   0ULL                                   // f32 [NC][BN][H]   4 MB
#define OFF_HIN  4194304ULL                             // f32 [NC][BN][H]   4 MB
#define OFF_WBF  8388608ULL                             // bf16 [768][256]   384 KB
#define OFF_DM   8781824ULL                             // u32 [NC][BN]      16 KB
#define OFF_XG   8798208ULL                             // bf16 xg2 tiled    192 MB
#define WS_NEED  210124800ULL

__device__ __forceinline__ unsigned short f2bf(float f) {   // RNE float->bf16
    union { float f; unsigned u; } v; v.f = f;
    unsigned u = v.u + 0x7FFFu + ((v.u >> 16) & 1u);
    return (unsigned short)(u >> 16);
}
__device__ __forceinline__ float bf2f(unsigned short h) {
    union { unsigned u; float f; } v; v.u = ((unsigned)h) << 16;
    return v.f;
}
__device__ __forceinline__ bf16x8 load_pack8(const float* __restrict__ p) {
    f32x4 a = *(const f32x4*)p;
    f32x4 b = *(const f32x4*)(p + 4);
    bf16x8 r;
    r[0]=(short)f2bf(a[0]); r[1]=(short)f2bf(a[1]); r[2]=(short)f2bf(a[2]); r[3]=(short)f2bf(a[3]);
    r[4]=(short)f2bf(b[0]); r[5]=(short)f2bf(b[1]); r[6]=(short)f2bf(b[2]); r[7]=(short)f2bf(b[3]);
    return r;
}
__device__ __forceinline__ float sigmoidf_(float x) { return 1.0f / (1.0f + __expf(-x)); }
__device__ __forceinline__ float tanhf_(float x)    { return 1.0f - 2.0f / (__expf(2.0f * x) + 1.0f); }

// Pin a bf16x8 fragment to the AGPR class (empty asm; builtin MFMA reads A
// from AGPR directly — AV operand class — with compiler-managed hazards).
__device__ __forceinline__ bf16x8 pin_a(bf16x8 v) {
    bf16x8 r;
    asm("" : "=a"(r) : "0"(v));
    return r;
}

// xg2 tiled layout: u16 index for element (tt, seq, g)
__device__ __forceinline__ size_t xg2_idx(int tt, int seq, int g) {
    return ((((size_t)tt * 32 + (seq >> 4)) * 48 + (g >> 4)) * 64
            + ((g >> 2) & 3) * 16 + (seq & 15)) * 4 + (g & 3);
}

// ---------------------------------------------------------------------------
// xg4: pipelined input-projection GEMM, 512 compute blocks = 2 blocks/CU
// (t = bid>>1, half = bid&1; each block owns 2 of the 4 128-seq tile groups).
// Double-buffered LDS; loads of group i+1 in flight under compute of group i.
// 2 co-resident blocks/CU overlap each other's staging/store stalls.
// Output layout bit-identical to round 11. Blocks >= 512: fused prep.
// ---------------------------------------------------------------------------
__global__ __launch_bounds__(512, 2)
void xg4_kernel(const float* __restrict__ x, const float* __restrict__ W_ih,
                const float* __restrict__ b_ih, const float* __restrict__ b_hh,
                const float* __restrict__ W_hh, const int* __restrict__ dones,
                unsigned short* __restrict__ xg2,
                unsigned short* __restrict__ wbf, unsigned int* __restrict__ dm)
{
    const int tid = threadIdx.x;
    if (blockIdx.x >= 512) {                        // ---- fused prep ----
        const int bid2 = blockIdx.x - 512;
        if (bid2 < 96) {                            // W_hh f32 -> bf16
            const int i4 = bid2 * 512 + tid;        // 49152 f32x4 units
            f32x4 w = ((const f32x4*)W_hh)[i4];
            u16x4 o;
            #pragma unroll
            for (int q = 0; q < 4; ++q) o[q] = f2bf(w[q]);
            ((u16x4*)wbf)[i4] = o;
        } else {                                    // done masks (u32, CL=32)
            const int u = (bid2 - 96) * 512 + tid;  // 4096 = NC*BN
            const int c = u >> 9, s = u & 511;
            unsigned m = 0;
            #pragma unroll
            for (int k = 0; k < CL_; ++k)
                m |= (dones[(c * CL_ + k) * BN_ + s] ? 1u : 0u) << k;
            dm[c * BN_ + s] = m;
        }
        return;
    }

    __shared__ __align__(16) unsigned short xls[2][128][136];   // 69.6 KB dbuf

    const int wave = tid >> 6, lane = tid & 63;
    const int lr = lane & 15, lg = lane >> 4;
    const int t    = blockIdx.x >> 1;               // timestep
    const int half = blockIdx.x & 1;                // tile-group pair 0/1
    const int g0 = wave * 96;

    // W_ih A-fragments (register-stationary) + biases
    bf16x8 wf[6][4];
    #pragma unroll
    for (int gt = 0; gt < 6; ++gt)
        #pragma unroll
        for (int kt = 0; kt < 4; ++kt)
            wf[gt][kt] = load_pack8(W_ih + (size_t)(g0 + gt*16 + lr) * F_ + kt*32 + lg*8);

    float bv[6][4];
    #pragma unroll
    for (int gt = 0; gt < 6; ++gt)
        #pragma unroll
        for (int q = 0; q < 4; ++q) {
            const int g = g0 + gt*16 + lg*4 + q;
            bv[gt][q] = b_ih[g] + (g < 2*H_ ? b_hh[g] : 0.0f);
        }

    // prologue: stage group (half*2) — 64 KB contiguous f32 read -> bf16 LDS
    {
        f32x4 sv0[8];
        #pragma unroll
        for (int s = 0; s < 8; ++s)
            sv0[s] = ((const f32x4*)x)[(size_t)t * 16384 + (size_t)(half*2) * 4096
                                       + s*512 + tid];
        #pragma unroll
        for (int s = 0; s < 8; ++s) {
            u16x4 o;
            #pragma unroll
            for (int q = 0; q < 4; ++q) o[q] = f2bf(sv0[s][q]);
            const int u = s*512 + tid;
            *(u16x4*)&xls[0][u >> 5][(u & 31) * 4] = o;
        }
    }
    __syncthreads();

    int buf = 0;
    #pragma unroll 1
    for (int i = 0; i < 2; ++i) {
        const int gi = half*2 + i;                  // global tile-group 0..3
        // 1. issue next group's loads (in flight under compute of group gi)
        f32x4 sv[8];
        if (i < 1) {
            #pragma unroll
            for (int s = 0; s < 8; ++s)
                sv[s] = ((const f32x4*)x)[(size_t)t * 16384 + (size_t)(gi+1) * 4096
                                          + s*512 + tid];
        }

        // 2. compute group gi: 8 seq-subtiles x (4 LDS frags, 24 MFMA, 6 stores)
        #pragma unroll
        for (int tbt = 0; tbt < 8; ++tbt) {
            bf16x8 xf[4];
            #pragma unroll
            for (int kt = 0; kt < 4; ++kt)
                xf[kt] = *(const bf16x8*)&xls[buf][tbt*16 + lr][kt*32 + lg*8];

            f32x4 acc[6];
            #pragma unroll
            for (int gt = 0; gt < 6; ++gt) acc[gt] = (f32x4){0.f, 0.f, 0.f, 0.f};

            #pragma unroll
            for (int kt = 0; kt < 4; ++kt)
                #pragma unroll
                for (int gt = 0; gt < 6; ++gt)
                    acc[gt] = __builtin_amdgcn_mfma_f32_16x16x32_bf16(wf[gt][kt], xf[kt], acc[gt], 0, 0, 0);

            const int sbg = gi*8 + tbt;             // global 16-seq subtile
            #pragma unroll
            for (int gt = 0; gt < 6; ++gt) {
                u16x4 o;
                #pragma unroll
                for (int q = 0; q < 4; ++q) o[q] = f2bf(acc[gt][q] + bv[gt][q]);
                const size_t base = (((size_t)t * 32 + sbg) * 48 + (wave*6 + gt)) * 64 + lane;
                *(u16x4*)(xg2 + base * 4) = o;
            }
        }

        // 3. convert + write staged next group into the other buffer
        if (i < 1) {
            #pragma unroll
            for (int s = 0; s < 8; ++s) {
                u16x4 o;
                #pragma unroll
                for (int q = 0; q < 4; ++q) o[q] = f2bf(sv[s][q]);
                const int u = s*512 + tid;
                *(u16x4*)&xls[buf ^ 1][u >> 5][(u & 31) * 4] = o;
            }
            __syncthreads();
        }
        buf ^= 1;
    }
}

// ---------------------------------------------------------------------------
// pass1 (round-11 verbatim): 256 thr = 4 waves, 1 block/CU. Wave w owns j in
// [64w,64w+64): r+z weights pinned to AGPR, n-gate in VGPRs, loaded ONCE.
// ---------------------------------------------------------------------------
__global__ __launch_bounds__(256, 1)
void pass1_kernel(const unsigned short* __restrict__ xg2,
                  const unsigned int*  __restrict__ dm,
                  const unsigned short* __restrict__ wbf,
                  const float* __restrict__ b_hh,
                  float* __restrict__ h1)
{
    __shared__ __align__(16) unsigned short hT[2][8][4][16][8];   // 16 KB
    __shared__ __align__(16) float hpL[16][260];                  // 16.6 KB
    __shared__ float bhnL[H_];                                    // 1 KB

    const int tid  = threadIdx.x;
    const int wave = tid >> 6, lane = tid & 63;
    const int lr = lane & 15, lg = lane >> 4;
    const int c   = blockIdx.x >> 5;            // 0..NC_-2
    const int bn0 = (blockIdx.x & 31) * 16;
    const int jb  = wave * 64;

    const unsigned m = dm[c * BN_ + bn0 + lr];
    if (__ballot(m != 0) == 0ULL) return;       // uniform across waves

    int last = m ? (31 - __builtin_clz(m)) : 31;
    #pragma unroll
    for (int w = 1; w < 16; w <<= 1) last = min(last, __shfl_xor(last, w));

    bhnL[tid] = b_hh[2*H_ + tid];
    #pragma unroll
    for (int sweep = 0; sweep < 2; ++sweep)
        ((bf16x8*)hT)[sweep * 256 + tid] = (bf16x8)(short)0;
    #pragma unroll
    for (int sweep = 0; sweep < 4; ++sweep) {
        const int u = sweep * 256 + tid, seq = u >> 6, jq = u & 63;
        *(f32x4*)&hpL[seq][jq * 4] = (f32x4){0.f, 0.f, 0.f, 0.f};
    }

    bf16x8 wfa[8][8];   // r+z -> AGPR
    bf16x8 wfv[4][8];   // n   -> VGPR
    #pragma unroll
    for (int mt = 0; mt < 8; ++mt) {
        const int row = (mt >> 2) * H_ + jb + (mt & 3) * 16 + lr;
        #pragma unroll
        for (int kt = 0; kt < 8; ++kt)
            wfa[mt][kt] = pin_a(*(const bf16x8*)(wbf + (size_t)row * H_ + kt*32 + lg*8));
    }
    #pragma unroll
    for (int ms = 0; ms < 4; ++ms) {
        const int row = 2 * H_ + jb + ms * 16 + lr;
        #pragma unroll
        for (int kt = 0; kt < 8; ++kt)
            wfv[ms][kt] = *(const bf16x8*)(wbf + (size_t)row * H_ + kt*32 + lg*8);
    }
    __syncthreads();

    const int sb = bn0 >> 4;
    int buf = 0;
    for (int t = last; t < CL_; ++t) {
        const int tt = c * CL_ + t;
        const int tb = (tt * 32 + sb) * 48;

        u16x4 xv[3][4];
        #pragma unroll
        for (int g = 0; g < 3; ++g)
            #pragma unroll
            for (int ms = 0; ms < 4; ++ms)
                xv[g][ms] = ((const u16x4*)xg2)[(size_t)(tb + g*16 + wave*4 + ms) * 64 + lane];

        const int d = (m >> t) & 1;
        const short dms = (short)(d ? 0 : -1);

        f32x4 acc[12];
        #pragma unroll
        for (int mt = 0; mt < 8; ++mt) acc[mt] = (f32x4){0.f, 0.f, 0.f, 0.f};
        #pragma unroll
        for (int ms = 0; ms < 4; ++ms)                 // n-gate seeded with b_hh_n
            acc[8 + ms] = *(const f32x4*)&bhnL[jb + ms*16 + lg*4];

        #pragma unroll
        for (int kt = 0; kt < 8; ++kt) {
            bf16x8 hv = *(const bf16x8*)&hT[buf][kt][lg][lr][0];
            hv = hv & dms;
            #pragma unroll
            for (int mt = 0; mt < 8; ++mt)
                acc[mt] = __builtin_amdgcn_mfma_f32_16x16x32_bf16(wfa[mt][kt], hv, acc[mt], 0, 0, 0);
            #pragma unroll
            for (int ms = 0; ms < 4; ++ms)
                acc[8 + ms] = __builtin_amdgcn_mfma_f32_16x16x32_bf16(wfv[ms][kt], hv, acc[8 + ms], 0, 0, 0);
        }

        #pragma unroll
        for (int ms = 0; ms < 4; ++ms) {
            const int jq = jb + ms*16 + lg*4;
            f32x4 hp4 = *(const f32x4*)&hpL[lr][jq];
            f32x4 hnew4; u16x4 hb;
            #pragma unroll
            for (int q = 0; q < 4; ++q) {
                float r = sigmoidf_(acc[0 + ms][q] + bf2f(xv[0][ms][q]));
                float z = sigmoidf_(acc[4 + ms][q] + bf2f(xv[1][ms][q]));
                float n = tanhf_(bf2f(xv[2][ms][q]) + r * acc[8 + ms][q]);
                float hpv = d ? 0.0f : hp4[q];
                float hn2 = n + z * (hpv - n);
                hnew4[q] = hn2; hb[q] = f2bf(hn2);
            }
            *(f32x4*)&hpL[lr][jq] = hnew4;
            *(u16x4*)&hT[buf ^ 1][jq >> 5][(jq >> 3) & 3][lr][jq & 7] = hb;
        }
        __syncthreads();
        buf ^= 1;
    }

    #pragma unroll
    for (int ms = 0; ms < 4; ++ms) {
        const int jq = jb + ms*16 + lg*4;
        f32x4 hv = *(const f32x4*)&hpL[lr][jq];
        *(f32x4*)(h1 + ((size_t)c * BN_ + bn0 + lr) * H_ + jq) = hv;
    }
}

// ---------------------------------------------------------------------------
// pass2: chain h across chunks. Copy when chunk has a done; rare VALU GRU.
// ---------------------------------------------------------------------------
__global__ __launch_bounds__(256)
void pass2_kernel(const unsigned short* __restrict__ xg2,
                  const unsigned int*  __restrict__ dm,
                  const unsigned short* __restrict__ wbf,
                  const float* __restrict__ b_hh,
                  const float* __restrict__ h0,
                  const float* __restrict__ h1,
                  float* __restrict__ hin)
{
    __shared__ unsigned short hsb[H_];
    const int s = blockIdx.x, j = threadIdx.x;
    float h = h0[(size_t)s * H_ + j];
    const float bhn = b_hh[2*H_ + j];

    for (int c = 0; c < NC_; ++c) {
        hin[((size_t)c * BN_ + s) * H_ + j] = h;
        if (c == NC_ - 1) break;
        const unsigned m = dm[c * BN_ + s];         // block-uniform
        if (m) {
            h = h1[((size_t)c * BN_ + s) * H_ + j];
        } else {
            for (int t = 0; t < CL_; ++t) {
                hsb[j] = f2bf(h);
                __syncthreads();
                float a0 = 0.f, a1 = 0.f, a2 = 0.f;
                for (int k = 0; k < H_; ++k) {
                    float hk = bf2f(hsb[k]);
                    a0 = fmaf(bf2f(wbf[(size_t)j * H_ + k]),          hk, a0);
                    a1 = fmaf(bf2f(wbf[(size_t)(H_ + j) * H_ + k]),   hk, a1);
                    a2 = fmaf(bf2f(wbf[(size_t)(2*H_ + j) * H_ + k]), hk, a2);
                }
                const int tt = c * CL_ + t;
                float xr = bf2f(xg2[xg2_idx(tt, s, j)]);
                float xz = bf2f(xg2[xg2_idx(tt, s, H_ + j)]);
                float xn = bf2f(xg2[xg2_idx(tt, s, 2*H_ + j)]);
                float r = sigmoidf_(a0 + xr);
                float z = sigmoidf_(a1 + xz);
                float n = tanhf_(xn + r * (a2 + bhn));
                h = n + z * (h - n);
                __syncthreads();
            }
        }
    }
}

// ---------------------------------------------------------------------------
// pass3 (round-11 verbatim, proven 187 us): from known h_in, compute outputs.
// ---------------------------------------------------------------------------
__global__ __launch_bounds__(256, 1)
void pass3_kernel(const unsigned short* __restrict__ xg2,
                  const unsigned int*  __restrict__ dm,
                  const unsigned short* __restrict__ wbf,
                  const float* __restrict__ b_hh,
                  const float* __restrict__ hin,
                  float* __restrict__ out)
{
    __shared__ __align__(16) unsigned short hT[2][8][4][16][8];   // 16 KB
    __shared__ __align__(16) float hpL[16][260];                  // 16.6 KB
    __shared__ float bhnL[H_];                                    // 1 KB

    const int tid  = threadIdx.x;
    const int wave = tid >> 6, lane = tid & 63;
    const int lr = lane & 15, lg = lane >> 4;
    const int c   = blockIdx.x >> 5;            // 0..NC_-1
    const int bn0 = (blockIdx.x & 31) * 16;
    const int jb  = wave * 64;

    const unsigned m = dm[c * BN_ + bn0 + lr];

    bhnL[tid] = b_hh[2*H_ + tid];
    // stage h_in: f32 -> hpL, bf16 -> hT[0]
    #pragma unroll
    for (int sweep = 0; sweep < 4; ++sweep) {
        const int u = sweep * 256 + tid, seq = u >> 6, jq = u & 63;
        f32x4 hv = ((const f32x4*)hin)[((size_t)c * BN_ + bn0 + seq) * 64 + jq];
        *(f32x4*)&hpL[seq][jq * 4] = hv;
    }
    #pragma unroll
    for (int sweep = 0; sweep < 2; ++sweep) {
        const int u = sweep * 256 + tid, col = u & 15, kb = (u >> 4) * 8;
        bf16x8 hv = load_pack8(hin + ((size_t)c * BN_ + bn0 + col) * H_ + kb);
        ((bf16x8*)hT)[u] = hv;
    }

    bf16x8 wfa[8][8];
    bf16x8 wfv[4][8];
    #pragma unroll
    for (int mt = 0; mt < 8; ++mt) {
        const int row = (mt >> 2) * H_ + jb + (mt & 3) * 16 + lr;
        #pragma unroll
        for (int kt = 0; kt < 8; ++kt)
            wfa[mt][kt] = pin_a(*(const bf16x8*)(wbf + (size_t)row * H_ + kt*32 + lg*8));
    }
    #pragma unroll
    for (int ms = 0; ms < 4; ++ms) {
        const int row = 2 * H_ + jb + ms * 16 + lr;
        #pragma unroll
        for (int kt = 0; kt < 8; ++kt)
            wfv[ms][kt] = *(const bf16x8*)(wbf + (size_t)row * H_ + kt*32 + lg*8);
    }
    __syncthreads();

    const int sb = bn0 >> 4;
    int buf = 0;
    for (int t = 0; t < CL_; ++t) {
        const int tt = c * CL_ + t;
        const int tb = (tt * 32 + sb) * 48;

        u16x4 xv[3][4];
        #pragma unroll
        for (int g = 0; g < 3; ++g)
            #pragma unroll
            for (int ms = 0; ms < 4; ++ms)
                xv[g][ms] = ((const u16x4*)xg2)[(size_t)(tb + g*16 + wave*4 + ms) * 64 + lane];

        const int d = (m >> t) & 1;
        const short dms = (short)(d ? 0 : -1);

        f32x4 acc[12];
        #pragma unroll
        for (int mt = 0; mt < 8; ++mt) acc[mt] = (f32x4){0.f, 0.f, 0.f, 0.f};
        #pragma unroll
        for (int ms = 0; ms < 4; ++ms)                 // n-gate seeded with b_hh_n
            acc[8 + ms] = *(const f32x4*)&bhnL[jb + ms*16 + lg*4];

        #pragma unroll
        for (int kt = 0; kt < 8; ++kt) {
            bf16x8 hv = *(const bf16x8*)&hT[buf][kt][lg][lr][0];
            hv = hv & dms;
            #pragma unroll
            for (int mt = 0; mt < 8; ++mt)
                acc[mt] = __builtin_amdgcn_mfma_f32_16x16x32_bf16(wfa[mt][kt], hv, acc[mt], 0, 0, 0);
            #pragma unroll
            for (int ms = 0; ms < 4; ++ms)
                acc[8 + ms] = __builtin_amdgcn_mfma_f32_16x16x32_bf16(wfv[ms][kt], hv, acc[8 + ms], 0, 0, 0);
        }

        #pragma unroll
        for (int ms = 0; ms < 4; ++ms) {
            const int jq = jb + ms*16 + lg*4;
            f32x4 hp4 = *(const f32x4*)&hpL[lr][jq];
            f32x4 hnew4; u16x4 hb;
            #pragma unroll
            for (int q = 0; q < 4; ++q) {
                float r = sigmoidf_(acc[0 + ms][q] + bf2f(xv[0][ms][q]));
                float z = sigmoidf_(acc[4 + ms][q] + bf2f(xv[1][ms][q]));
                float n = tanhf_(bf2f(xv[2][ms][q]) + r * acc[8 + ms][q]);
                float hpv = d ? 0.0f : hp4[q];
                float hn2 = n + z * (hpv - n);
                hnew4[q] = hn2; hb[q] = f2bf(hn2);
            }
            *(f32x4*)&hpL[lr][jq] = hnew4;
            *(u16x4*)&hT[buf ^ 1][jq >> 5][(jq >> 3) & 3][lr][jq & 7] = hb;
            *(f32x4*)(out + ((size_t)tt * BN_ + bn0 + lr) * H_ + jq) = hnew4;
        }
        __syncthreads();
        buf ^= 1;
    }

    if (c == NC_ - 1) {
        #pragma unroll
        for (int ms = 0; ms < 4; ++ms) {
            const int jq = jb + ms*16 + lg*4;
            f32x4 hv = *(const f32x4*)&hpL[lr][jq];
            *(f32x4*)(out + (size_t)T_ * BN_ * H_ + (size_t)(bn0 + lr) * H_ + jq) = hv;
        }
    }
}

// ---------------------------------------------------------------------------
// Fallback (ws too small): fp32 VALU persistent kernel (correct, slow)
// ---------------------------------------------------------------------------
#define SPB 4
__global__ __launch_bounds__(256, 1)
void slotgru_fallback(const float* __restrict__ x, const int* __restrict__ dones,
                      const float* __restrict__ h0, const float* __restrict__ W_ih,
                      const float* __restrict__ W_hh, const float* __restrict__ b_ih,
                      const float* __restrict__ b_hh, float* __restrict__ out)
{
    __shared__ __align__(16) float xs[SPB][F_];
    __shared__ __align__(16) float hs[SPB][H_];
    const int j = threadIdx.x, bn0 = blockIdx.x * SPB;
    const float bi0 = b_ih[j], bi1 = b_ih[H_ + j], bi2 = b_ih[2*H_ + j];
    const float bh0 = b_hh[j], bh1 = b_hh[H_ + j], bh2 = b_hh[2*H_ + j];
    const float4* wi0 = (const float4*)(W_ih + (size_t)j * F_);
    const float4* wi1 = (const float4*)(W_ih + (size_t)(H_ + j) * F_);
    const float4* wi2 = (const float4*)(W_ih + (size_t)(2*H_ + j) * F_);
    const float4* wh0 = (const float4*)(W_hh + (size_t)j * H_);
    const float4* wh1 = (const float4*)(W_hh + (size_t)(H_ + j) * H_);
    const float4* wh2 = (const float4*)(W_hh + (size_t)(2*H_ + j) * H_);
    float hreg[SPB];
    #pragma unroll
    for (int s = 0; s < SPB; ++s) { float h = h0[(size_t)(bn0+s)*H_ + j]; hreg[s]=h; hs[s][j]=h; }
    for (int t = 0; t < T_; ++t) {
        int d[SPB];
        #pragma unroll
        for (int s = 0; s < SPB; ++s) d[s] = dones[(size_t)t*BN_ + bn0 + s];
        const float* xsrc = x + (size_t)((size_t)t*BN_ + bn0) * F_;
        ((float*)xs)[j] = xsrc[j]; ((float*)xs)[j+256] = xsrc[j+256];
        #pragma unroll
        for (int s = 0; s < SPB; ++s) if (d[s]) hs[s][j] = 0.0f;
        __syncthreads();
        float ax0[SPB]={0,0,0,0}, ax1[SPB]={0,0,0,0}, ax2[SPB]={0,0,0,0};
        #pragma unroll 8
        for (int cc = 0; cc < F_/4; ++cc) {
            float4 w0=wi0[cc], w1=wi1[cc], w2=wi2[cc];
            #pragma unroll
            for (int s = 0; s < SPB; ++s) {
                float4 xv = ((const float4*)xs[s])[cc];
                ax0[s]=fmaf(w0.x,xv.x,fmaf(w0.y,xv.y,fmaf(w0.z,xv.z,fmaf(w0.w,xv.w,ax0[s]))));
                ax1[s]=fmaf(w1.x,xv.x,fmaf(w1.y,xv.y,fmaf(w1.z,xv.z,fmaf(w1.w,xv.w,ax1[s]))));
                ax2[s]=fmaf(w2.x,xv.x,fmaf(w2.y,xv.y,fmaf(w2.z,xv.z,fmaf(w2.w,xv.w,ax2[s]))));
            }
        }
        float ah0[SPB]={0,0,0,0}, ah1[SPB]={0,0,0,0}, ah2[SPB]={0,0,0,0};
        if (!(d[0]&&d[1]&&d[2]&&d[3])) {
            #pragma unroll 4
            for (int cc = 0; cc < H_/4; ++cc) {
                float4 w0=wh0[cc], w1=wh1[cc], w2=wh2[cc];
                #pragma unroll
                for (int s = 0; s < SPB; ++s) if (!d[s]) {
                    float4 hv = ((const float4*)hs[s])[cc];
                    ah0[s]=fmaf(w0.x,hv.x,fmaf(w0.y,hv.y,fmaf(w0.z,hv.z,fmaf(w0.w,hv.w,ah0[s]))));
                    ah1[s]=fmaf(w1.x,hv.x,fmaf(w1.y,hv.y,fmaf(w1.z,hv.z,fmaf(w1.w,hv.w,ah1[s]))));
                    ah2[s]=fmaf(w2.x,hv.x,fmaf(w2.y,hv.y,fmaf(w2.z,hv.z,fmaf(w2.w,hv.w,ah2[s]))));
                }
            }
        }
        float hnew[SPB];
        #pragma unroll
        for (int s = 0; s < SPB; ++s) {
            float hpv = d[s] ? 0.0f : hreg[s];
            float r = sigmoidf_(ax0[s] + bi0 + ah0[s] + bh0);
            float z = sigmoidf_(ax1[s] + bi1 + ah1[s] + bh1);
            float n = tanhf_(ax2[s] + bi2 + r * (ah2[s] + bh2));
            hnew[s] = (1.0f - z) * n + z * hpv;
        }
        __syncthreads();
        #pragma unroll
        for (int s = 0; s < SPB; ++s) {
            hs[s][j] = hnew[s]; hreg[s] = hnew[s];
            out[(size_t)((size_t)t*BN_ + bn0 + s) * H_ + j] = hnew[s];
        }
    }
    #pragma unroll
    for (int s = 0; s < SPB; ++s)
        out[(size_t)T_*BN_*H_ + (size_t)(bn0+s)*H_ + j] = hreg[s];
}

extern "C" void kernel_launch(void* const* d_in, const int* in_sizes, int n_in,
                              void* d_out, int out_size, void* d_ws, size_t ws_size,
                              hipStream_t stream) {
    const float* x     = (const float*)d_in[0];
    const int*   dones = (const int*)  d_in[1];
    const float* h0    = (const float*)d_in[2];
    const float* W_ih  = (const float*)d_in[3];
    const float* W_hh  = (const float*)d_in[4];
    const float* b_ih  = (const float*)d_in[5];
    const float* b_hh  = (const float*)d_in[6];
    float*       out   = (float*)d_out;

    if (ws_size >= WS_NEED) {
        char* ws = (char*)d_ws;
        float*          h1  = (float*)(ws + OFF_H1);
        float*          hin = (float*)(ws + OFF_HIN);
        unsigned short* wbf = (unsigned short*)(ws + OFF_WBF);
        unsigned int*   dmm = (unsigned int*)(ws + OFF_DM);
        unsigned short* xg2 = (unsigned short*)(ws + OFF_XG);

        hipLaunchKernelGGL(xg4_kernel, dim3(512 + 104), dim3(512), 0, stream,
                           x, W_ih, b_ih, b_hh, W_hh, dones, xg2, wbf, dmm);
        hipLaunchKernelGGL(pass1_kernel, dim3((NC_ - 1) * 32), dim3(256), 0, stream,
                           xg2, dmm, wbf, b_hh, h1);
        hipLaunchKernelGGL(pass2_kernel, dim3(BN_), dim3(256), 0, stream,
                           xg2, dmm, wbf, b_hh, h0, h1, hin);
        hipLaunchKernelGGL(pass3_kernel, dim3(NC_ * 32), dim3(256), 0, stream,
                           xg2, dmm, wbf, b_hh, hin, out);
    } else {
        hipLaunchKernelGGL(slotgru_fallback, dim3(BN_ / SPB), dim3(256), 0, stream,
                           x, dones, h0, W_ih, W_hh, b_ih, b_hh, out);
    }
}

// Round 15
// 270.116 us; speedup vs baseline: 1.4328x; 1.2389x over previous
//
#include <hip/hip_runtime.h>
#include <math.h>

#define T_   256
#define B_   32
#define N_   16
#define F_   128
#define H_   256
#define BN_  512          // B*N
#define G3_  768          // 3*H
#define CL_  32           // chunk length
#define NC_  8            // number of chunks (T_/CL_)

typedef __attribute__((ext_vector_type(8))) short  bf16x8;
typedef __attribute__((ext_vector_type(4))) float  f32x4;
typedef __attribute__((ext_vector_type(4))) unsigned short u16x4;

// ---- workspace layout (bytes) ----  (identical to round 6/11)
#define OFF_H1   0ULL                                   // f32 [NC][BN][H]   4 MB
#define OFF_HIN  4194304ULL                             // f32 [NC][BN][H]   4 MB
#define OFF_WBF  8388608ULL                             // bf16 [768][256]   384 KB
#define OFF_DM   8781824ULL                             // u32 [NC][BN]      16 KB
#define OFF_XG   8798208ULL                             // bf16 xg2 tiled    192 MB
#define WS_NEED  210124800ULL

__device__ __forceinline__ unsigned short f2bf(float f) {   // RNE float->bf16
    union { float f; unsigned u; } v; v.f = f;
    unsigned u = v.u + 0x7FFFu + ((v.u >> 16) & 1u);
    return (unsigned short)(u >> 16);
}
__device__ __forceinline__ float bf2f(unsigned short h) {
    union { unsigned u; float f; } v; v.u = ((unsigned)h) << 16;
    return v.f;
}
__device__ __forceinline__ bf16x8 load_pack8(const float* __restrict__ p) {
    f32x4 a = *(const f32x4*)p;
    f32x4 b = *(const f32x4*)(p + 4);
    bf16x8 r;
    r[0]=(short)f2bf(a[0]); r[1]=(short)f2bf(a[1]); r[2]=(short)f2bf(a[2]); r[3]=(short)f2bf(a[3]);
    r[4]=(short)f2bf(b[0]); r[5]=(short)f2bf(b[1]); r[6]=(short)f2bf(b[2]); r[7]=(short)f2bf(b[3]);
    return r;
}

// Fast 1/x via v_rcp_f32 (1 ULP). Replaces the IEEE div sequence
// (v_div_scale/fmas/fixup, ~12 instr) -> 1 instr. rcp(inf)=0 gives correct
// gate saturation. 1e-7 rel error << bf16 rounding (4e-3).
__device__ __forceinline__ float fast_rcp(float x) { return __builtin_amdgcn_rcpf(x); }
__device__ __forceinline__ float sigmoidf_(float x) { return fast_rcp(1.0f + __expf(-x)); }
__device__ __forceinline__ float tanhf_(float x)    { return 1.0f - 2.0f * fast_rcp(__expf(2.0f * x) + 1.0f); }

// Pin a bf16x8 fragment to the AGPR class (empty asm; builtin MFMA reads A
// from AGPR directly — AV operand class — with compiler-managed hazards).
__device__ __forceinline__ bf16x8 pin_a(bf16x8 v) {
    bf16x8 r;
    asm("" : "=a"(r) : "0"(v));
    return r;
}

// xg2 tiled layout: u16 index for element (tt, seq, g)
__device__ __forceinline__ size_t xg2_idx(int tt, int seq, int g) {
    return ((((size_t)tt * 32 + (seq >> 4)) * 48 + (g >> 4)) * 64
            + ((g >> 2) & 3) * 16 + (seq & 15)) * 4 + (g & 3);
}

// ---------------------------------------------------------------------------
// xg3: pipelined input-projection GEMM (round-11 proven, ~90 us). 256
// persistent compute blocks (1/CU, 512 thr), double-buffered LDS, loads of
// tile i+1 in flight under compute of tile i. Blocks >= 256: fused prep.
// ---------------------------------------------------------------------------
__global__ __launch_bounds__(512, 2)
void xg3_kernel(const float* __restrict__ x, const float* __restrict__ W_ih,
                const float* __restrict__ b_ih, const float* __restrict__ b_hh,
                const float* __restrict__ W_hh, const int* __restrict__ dones,
                unsigned short* __restrict__ xg2,
                unsigned short* __restrict__ wbf, unsigned int* __restrict__ dm)
{
    const int tid = threadIdx.x;
    if (blockIdx.x >= 256) {                        // ---- fused prep ----
        const int bid2 = blockIdx.x - 256;
        if (bid2 < 96) {                            // W_hh f32 -> bf16
            const int i4 = bid2 * 512 + tid;        // 49152 f32x4 units
            f32x4 w = ((const f32x4*)W_hh)[i4];
            u16x4 o;
            #pragma unroll
            for (int q = 0; q < 4; ++q) o[q] = f2bf(w[q]);
            ((u16x4*)wbf)[i4] = o;
        } else {                                    // done masks (u32, CL=32)
            const int u = (bid2 - 96) * 512 + tid;  // 4096 = NC*BN
            const int c = u >> 9, s = u & 511;
            unsigned m = 0;
            #pragma unroll
            for (int k = 0; k < CL_; ++k)
                m |= (dones[(c * CL_ + k) * BN_ + s] ? 1u : 0u) << k;
            dm[c * BN_ + s] = m;
        }
        return;
    }

    __shared__ __align__(16) unsigned short xls[2][128][136];   // 69.6 KB dbuf

    const int wave = tid >> 6, lane = tid & 63;
    const int lr = lane & 15, lg = lane >> 4;
    const int t  = blockIdx.x;                      // one timestep per block
    const int g0 = wave * 96;

    bf16x8 wf[6][4];
    #pragma unroll
    for (int gt = 0; gt < 6; ++gt)
        #pragma unroll
        for (int kt = 0; kt < 4; ++kt)
            wf[gt][kt] = load_pack8(W_ih + (size_t)(g0 + gt*16 + lr) * F_ + kt*32 + lg*8);

    float bv[6][4];
    #pragma unroll
    for (int gt = 0; gt < 6; ++gt)
        #pragma unroll
        for (int q = 0; q < 4; ++q) {
            const int g = g0 + gt*16 + lg*4 + q;
            bv[gt][q] = b_ih[g] + (g < 2*H_ ? b_hh[g] : 0.0f);
        }

    {
        f32x4 sv0[8];
        #pragma unroll
        for (int s = 0; s < 8; ++s)
            sv0[s] = ((const f32x4*)x)[(size_t)t * 16384 + s*512 + tid];
        #pragma unroll
        for (int s = 0; s < 8; ++s) {
            u16x4 o;
            #pragma unroll
            for (int q = 0; q < 4; ++q) o[q] = f2bf(sv0[s][q]);
            const int u = s*512 + tid;
            *(u16x4*)&xls[0][u >> 5][(u & 31) * 4] = o;
        }
    }
    __syncthreads();

    int buf = 0;
    #pragma unroll 1
    for (int i = 0; i < 4; ++i) {
        f32x4 sv[8];
        if (i < 3) {
            #pragma unroll
            for (int s = 0; s < 8; ++s)
                sv[s] = ((const f32x4*)x)[(size_t)t * 16384 + (i+1)*4096 + s*512 + tid];
        }

        #pragma unroll
        for (int tbt = 0; tbt < 8; ++tbt) {
            bf16x8 xf[4];
            #pragma unroll
            for (int kt = 0; kt < 4; ++kt)
                xf[kt] = *(const bf16x8*)&xls[buf][tbt*16 + lr][kt*32 + lg*8];

            f32x4 acc[6];
            #pragma unroll
            for (int gt = 0; gt < 6; ++gt) acc[gt] = (f32x4){0.f, 0.f, 0.f, 0.f};

            #pragma unroll
            for (int kt = 0; kt < 4; ++kt)
                #pragma unroll
                for (int gt = 0; gt < 6; ++gt)
                    acc[gt] = __builtin_amdgcn_mfma_f32_16x16x32_bf16(wf[gt][kt], xf[kt], acc[gt], 0, 0, 0);

            const int sbg = i*8 + tbt;
            #pragma unroll
            for (int gt = 0; gt < 6; ++gt) {
                u16x4 o;
                #pragma unroll
                for (int q = 0; q < 4; ++q) o[q] = f2bf(acc[gt][q] + bv[gt][q]);
                const size_t base = (((size_t)t * 32 + sbg) * 48 + (wave*6 + gt)) * 64 + lane;
                *(u16x4*)(xg2 + base * 4) = o;
            }
        }

        if (i < 3) {
            #pragma unroll
            for (int s = 0; s < 8; ++s) {
                u16x4 o;
                #pragma unroll
                for (int q = 0; q < 4; ++q) o[q] = f2bf(sv[s][q]);
                const int u = s*512 + tid;
                *(u16x4*)&xls[buf ^ 1][u >> 5][(u & 31) * 4] = o;
            }
            __syncthreads();
        }
        buf ^= 1;
    }
}

// ---------------------------------------------------------------------------
// pass1 (round-11 structure): 256 thr = 4 waves, 1 block/CU. Wave w owns j in
// [64w,64w+64): r+z weights pinned to AGPR, n-gate in VGPRs, loaded ONCE.
// ---------------------------------------------------------------------------
__global__ __launch_bounds__(256, 1)
void pass1_kernel(const unsigned short* __restrict__ xg2,
                  const unsigned int*  __restrict__ dm,
                  const unsigned short* __restrict__ wbf,
                  const float* __restrict__ b_hh,
                  float* __restrict__ h1)
{
    __shared__ __align__(16) unsigned short hT[2][8][4][16][8];   // 16 KB
    __shared__ __align__(16) float hpL[16][260];                  // 16.6 KB
    __shared__ float bhnL[H_];                                    // 1 KB

    const int tid  = threadIdx.x;
    const int wave = tid >> 6, lane = tid & 63;
    const int lr = lane & 15, lg = lane >> 4;
    const int c   = blockIdx.x >> 5;            // 0..NC_-2
    const int bn0 = (blockIdx.x & 31) * 16;
    const int jb  = wave * 64;

    const unsigned m = dm[c * BN_ + bn0 + lr];
    if (__ballot(m != 0) == 0ULL) return;       // uniform across waves

    int last = m ? (31 - __builtin_clz(m)) : 31;
    #pragma unroll
    for (int w = 1; w < 16; w <<= 1) last = min(last, __shfl_xor(last, w));

    bhnL[tid] = b_hh[2*H_ + tid];
    #pragma unroll
    for (int sweep = 0; sweep < 2; ++sweep)
        ((bf16x8*)hT)[sweep * 256 + tid] = (bf16x8)(short)0;
    #pragma unroll
    for (int sweep = 0; sweep < 4; ++sweep) {
        const int u = sweep * 256 + tid, seq = u >> 6, jq = u & 63;
        *(f32x4*)&hpL[seq][jq * 4] = (f32x4){0.f, 0.f, 0.f, 0.f};
    }

    bf16x8 wfa[8][8];   // r+z -> AGPR
    bf16x8 wfv[4][8];   // n   -> VGPR
    #pragma unroll
    for (int mt = 0; mt < 8; ++mt) {
        const int row = (mt >> 2) * H_ + jb + (mt & 3) * 16 + lr;
        #pragma unroll
        for (int kt = 0; kt < 8; ++kt)
            wfa[mt][kt] = pin_a(*(const bf16x8*)(wbf + (size_t)row * H_ + kt*32 + lg*8));
    }
    #pragma unroll
    for (int ms = 0; ms < 4; ++ms) {
        const int row = 2 * H_ + jb + ms * 16 + lr;
        #pragma unroll
        for (int kt = 0; kt < 8; ++kt)
            wfv[ms][kt] = *(const bf16x8*)(wbf + (size_t)row * H_ + kt*32 + lg*8);
    }
    __syncthreads();

    const int sb = bn0 >> 4;
    int buf = 0;
    for (int t = last; t < CL_; ++t) {
        const int tt = c * CL_ + t;
        const int tb = (tt * 32 + sb) * 48;

        u16x4 xv[3][4];
        #pragma unroll
        for (int g = 0; g < 3; ++g)
            #pragma unroll
            for (int ms = 0; ms < 4; ++ms)
                xv[g][ms] = ((const u16x4*)xg2)[(size_t)(tb + g*16 + wave*4 + ms) * 64 + lane];

        const int d = (m >> t) & 1;
        const short dms = (short)(d ? 0 : -1);

        f32x4 acc[12];
        #pragma unroll
        for (int mt = 0; mt < 8; ++mt) acc[mt] = (f32x4){0.f, 0.f, 0.f, 0.f};
        #pragma unroll
        for (int ms = 0; ms < 4; ++ms)                 // n-gate seeded with b_hh_n
            acc[8 + ms] = *(const f32x4*)&bhnL[jb + ms*16 + lg*4];

        #pragma unroll
        for (int kt = 0; kt < 8; ++kt) {
            bf16x8 hv = *(const bf16x8*)&hT[buf][kt][lg][lr][0];
            hv = hv & dms;
            #pragma unroll
            for (int mt = 0; mt < 8; ++mt)
                acc[mt] = __builtin_amdgcn_mfma_f32_16x16x32_bf16(wfa[mt][kt], hv, acc[mt], 0, 0, 0);
            #pragma unroll
            for (int ms = 0; ms < 4; ++ms)
                acc[8 + ms] = __builtin_amdgcn_mfma_f32_16x16x32_bf16(wfv[ms][kt], hv, acc[8 + ms], 0, 0, 0);
        }

        #pragma unroll
        for (int ms = 0; ms < 4; ++ms) {
            const int jq = jb + ms*16 + lg*4;
            f32x4 hp4 = *(const f32x4*)&hpL[lr][jq];
            f32x4 hnew4; u16x4 hb;
            #pragma unroll
            for (int q = 0; q < 4; ++q) {
                float r = sigmoidf_(acc[0 + ms][q] + bf2f(xv[0][ms][q]));
                float z = sigmoidf_(acc[4 + ms][q] + bf2f(xv[1][ms][q]));
                float n = tanhf_(bf2f(xv[2][ms][q]) + r * acc[8 + ms][q]);
                float hpv = d ? 0.0f : hp4[q];
                float hn2 = n + z * (hpv - n);
                hnew4[q] = hn2; hb[q] = f2bf(hn2);
            }
            *(f32x4*)&hpL[lr][jq] = hnew4;
            *(u16x4*)&hT[buf ^ 1][jq >> 5][(jq >> 3) & 3][lr][jq & 7] = hb;
        }
        __syncthreads();
        buf ^= 1;
    }

    #pragma unroll
    for (int ms = 0; ms < 4; ++ms) {
        const int jq = jb + ms*16 + lg*4;
        f32x4 hv = *(const f32x4*)&hpL[lr][jq];
        *(f32x4*)(h1 + ((size_t)c * BN_ + bn0 + lr) * H_ + jq) = hv;
    }
}

// ---------------------------------------------------------------------------
// pass2: chain h across chunks. Copy when chunk has a done; rare VALU GRU.
// ---------------------------------------------------------------------------
__global__ __launch_bounds__(256)
void pass2_kernel(const unsigned short* __restrict__ xg2,
                  const unsigned int*  __restrict__ dm,
                  const unsigned short* __restrict__ wbf,
                  const float* __restrict__ b_hh,
                  const float* __restrict__ h0,
                  const float* __restrict__ h1,
                  float* __restrict__ hin)
{
    __shared__ unsigned short hsb[H_];
    const int s = blockIdx.x, j = threadIdx.x;
    float h = h0[(size_t)s * H_ + j];
    const float bhn = b_hh[2*H_ + j];

    for (int c = 0; c < NC_; ++c) {
        hin[((size_t)c * BN_ + s) * H_ + j] = h;
        if (c == NC_ - 1) break;
        const unsigned m = dm[c * BN_ + s];         // block-uniform
        if (m) {
            h = h1[((size_t)c * BN_ + s) * H_ + j];
        } else {
            for (int t = 0; t < CL_; ++t) {
                hsb[j] = f2bf(h);
                __syncthreads();
                float a0 = 0.f, a1 = 0.f, a2 = 0.f;
                for (int k = 0; k < H_; ++k) {
                    float hk = bf2f(hsb[k]);
                    a0 = fmaf(bf2f(wbf[(size_t)j * H_ + k]),          hk, a0);
                    a1 = fmaf(bf2f(wbf[(size_t)(H_ + j) * H_ + k]),   hk, a1);
                    a2 = fmaf(bf2f(wbf[(size_t)(2*H_ + j) * H_ + k]), hk, a2);
                }
                const int tt = c * CL_ + t;
                float xr = bf2f(xg2[xg2_idx(tt, s, j)]);
                float xz = bf2f(xg2[xg2_idx(tt, s, H_ + j)]);
                float xn = bf2f(xg2[xg2_idx(tt, s, 2*H_ + j)]);
                float r = sigmoidf_(a0 + xr);
                float z = sigmoidf_(a1 + xz);
                float n = tanhf_(xn + r * (a2 + bhn));
                h = n + z * (h - n);
                __syncthreads();
            }
        }
    }
}

// ---------------------------------------------------------------------------
// pass3 (round-11 structure, proven 187 us): from known h_in, compute outputs.
// ---------------------------------------------------------------------------
__global__ __launch_bounds__(256, 1)
void pass3_kernel(const unsigned short* __restrict__ xg2,
                  const unsigned int*  __restrict__ dm,
                  const unsigned short* __restrict__ wbf,
                  const float* __restrict__ b_hh,
                  const float* __restrict__ hin,
                  float* __restrict__ out)
{
    __shared__ __align__(16) unsigned short hT[2][8][4][16][8];   // 16 KB
    __shared__ __align__(16) float hpL[16][260];                  // 16.6 KB
    __shared__ float bhnL[H_];                                    // 1 KB

    const int tid  = threadIdx.x;
    const int wave = tid >> 6, lane = tid & 63;
    const int lr = lane & 15, lg = lane >> 4;
    const int c   = blockIdx.x >> 5;            // 0..NC_-1
    const int bn0 = (blockIdx.x & 31) * 16;
    const int jb  = wave * 64;

    const unsigned m = dm[c * BN_ + bn0 + lr];

    bhnL[tid] = b_hh[2*H_ + tid];
    // stage h_in: f32 -> hpL, bf16 -> hT[0]
    #pragma unroll
    for (int sweep = 0; sweep < 4; ++sweep) {
        const int u = sweep * 256 + tid, seq = u >> 6, jq = u & 63;
        f32x4 hv = ((const f32x4*)hin)[((size_t)c * BN_ + bn0 + seq) * 64 + jq];
        *(f32x4*)&hpL[seq][jq * 4] = hv;
    }
    #pragma unroll
    for (int sweep = 0; sweep < 2; ++sweep) {
        const int u = sweep * 256 + tid, col = u & 15, kb = (u >> 4) * 8;
        bf16x8 hv = load_pack8(hin + ((size_t)c * BN_ + bn0 + col) * H_ + kb);
        ((bf16x8*)hT)[u] = hv;
    }

    bf16x8 wfa[8][8];
    bf16x8 wfv[4][8];
    #pragma unroll
    for (int mt = 0; mt < 8; ++mt) {
        const int row = (mt >> 2) * H_ + jb + (mt & 3) * 16 + lr;
        #pragma unroll
        for (int kt = 0; kt < 8; ++kt)
            wfa[mt][kt] = pin_a(*(const bf16x8*)(wbf + (size_t)row * H_ + kt*32 + lg*8));
    }
    #pragma unroll
    for (int ms = 0; ms < 4; ++ms) {
        const int row = 2 * H_ + jb + ms * 16 + lr;
        #pragma unroll
        for (int kt = 0; kt < 8; ++kt)
            wfv[ms][kt] = *(const bf16x8*)(wbf + (size_t)row * H_ + kt*32 + lg*8);
    }
    __syncthreads();

    const int sb = bn0 >> 4;
    int buf = 0;
    for (int t = 0; t < CL_; ++t) {
        const int tt = c * CL_ + t;
        const int tb = (tt * 32 + sb) * 48;

        u16x4 xv[3][4];
        #pragma unroll
        for (int g = 0; g < 3; ++g)
            #pragma unroll
            for (int ms = 0; ms < 4; ++ms)
                xv[g][ms] = ((const u16x4*)xg2)[(size_t)(tb + g*16 + wave*4 + ms) * 64 + lane];

        const int d = (m >> t) & 1;
        const short dms = (short)(d ? 0 : -1);

        f32x4 acc[12];
        #pragma unroll
        for (int mt = 0; mt < 8; ++mt) acc[mt] = (f32x4){0.f, 0.f, 0.f, 0.f};
        #pragma unroll
        for (int ms = 0; ms < 4; ++ms)                 // n-gate seeded with b_hh_n
            acc[8 + ms] = *(const f32x4*)&bhnL[jb + ms*16 + lg*4];

        #pragma unroll
        for (int kt = 0; kt < 8; ++kt) {
            bf16x8 hv = *(const bf16x8*)&hT[buf][kt][lg][lr][0];
            hv = hv & dms;
            #pragma unroll
            for (int mt = 0; mt < 8; ++mt)
                acc[mt] = __builtin_amdgcn_mfma_f32_16x16x32_bf16(wfa[mt][kt], hv, acc[mt], 0, 0, 0);
            #pragma unroll
            for (int ms = 0; ms < 4; ++ms)
                acc[8 + ms] = __builtin_amdgcn_mfma_f32_16x16x32_bf16(wfv[ms][kt], hv, acc[8 + ms], 0, 0, 0);
        }

        #pragma unroll
        for (int ms = 0; ms < 4; ++ms) {
            const int jq = jb + ms*16 + lg*4;
            f32x4 hp4 = *(const f32x4*)&hpL[lr][jq];
            f32x4 hnew4; u16x4 hb;
            #pragma unroll
            for (int q = 0; q < 4; ++q) {
                float r = sigmoidf_(acc[0 + ms][q] + bf2f(xv[0][ms][q]));
                float z = sigmoidf_(acc[4 + ms][q] + bf2f(xv[1][ms][q]));
                float n = tanhf_(bf2f(xv[2][ms][q]) + r * acc[8 + ms][q]);
                float hpv = d ? 0.0f : hp4[q];
                float hn2 = n + z * (hpv - n);
                hnew4[q] = hn2; hb[q] = f2bf(hn2);
            }
            *(f32x4*)&hpL[lr][jq] = hnew4;
            *(u16x4*)&hT[buf ^ 1][jq >> 5][(jq >> 3) & 3][lr][jq & 7] = hb;
            *(f32x4*)(out + ((size_t)tt * BN_ + bn0 + lr) * H_ + jq) = hnew4;
        }
        __syncthreads();
        buf ^= 1;
    }

    if (c == NC_ - 1) {
        #pragma unroll
        for (int ms = 0; ms < 4; ++ms) {
            const int jq = jb + ms*16 + lg*4;
            f32x4 hv = *(const f32x4*)&hpL[lr][jq];
            *(f32x4*)(out + (size_t)T_ * BN_ * H_ + (size_t)(bn0 + lr) * H_ + jq) = hv;
        }
    }
}

// ---------------------------------------------------------------------------
// Fallback (ws too small): fp32 VALU persistent kernel (correct, slow)
// ---------------------------------------------------------------------------
#define SPB 4
__global__ __launch_bounds__(256, 1)
void slotgru_fallback(const float* __restrict__ x, const int* __restrict__ dones,
                      const float* __restrict__ h0, const float* __restrict__ W_ih,
                      const float* __restrict__ W_hh, const float* __restrict__ b_ih,
                      const float* __restrict__ b_hh, float* __restrict__ out)
{
    __shared__ __align__(16) float xs[SPB][F_];
    __shared__ __align__(16) float hs[SPB][H_];
    const int j = threadIdx.x, bn0 = blockIdx.x * SPB;
    const float bi0 = b_ih[j], bi1 = b_ih[H_ + j], bi2 = b_ih[2*H_ + j];
    const float bh0 = b_hh[j], bh1 = b_hh[H_ + j], bh2 = b_hh[2*H_ + j];
    const float4* wi0 = (const float4*)(W_ih + (size_t)j * F_);
    const float4* wi1 = (const float4*)(W_ih + (size_t)(H_ + j) * F_);
    const float4* wi2 = (const float4*)(W_ih + (size_t)(2*H_ + j) * F_);
    const float4* wh0 = (const float4*)(W_hh + (size_t)j * H_);
    const float4* wh1 = (const float4*)(W_hh + (size_t)(H_ + j) * H_);
    const float4* wh2 = (const float4*)(W_hh + (size_t)(2*H_ + j) * H_);
    float hreg[SPB];
    #pragma unroll
    for (int s = 0; s < SPB; ++s) { float h = h0[(size_t)(bn0+s)*H_ + j]; hreg[s]=h; hs[s][j]=h; }
    for (int t = 0; t < T_; ++t) {
        int d[SPB];
        #pragma unroll
        for (int s = 0; s < SPB; ++s) d[s] = dones[(size_t)t*BN_ + bn0 + s];
        const float* xsrc = x + (size_t)((size_t)t*BN_ + bn0) * F_;
        ((float*)xs)[j] = xsrc[j]; ((float*)xs)[j+256] = xsrc[j+256];
        #pragma unroll
        for (int s = 0; s < SPB; ++s) if (d[s]) hs[s][j] = 0.0f;
        __syncthreads();
        float ax0[SPB]={0,0,0,0}, ax1[SPB]={0,0,0,0}, ax2[SPB]={0,0,0,0};
        #pragma unroll 8
        for (int cc = 0; cc < F_/4; ++cc) {
            float4 w0=wi0[cc], w1=wi1[cc], w2=wi2[cc];
            #pragma unroll
            for (int s = 0; s < SPB; ++s) {
                float4 xv = ((const float4*)xs[s])[cc];
                ax0[s]=fmaf(w0.x,xv.x,fmaf(w0.y,xv.y,fmaf(w0.z,xv.z,fmaf(w0.w,xv.w,ax0[s]))));
                ax1[s]=fmaf(w1.x,xv.x,fmaf(w1.y,xv.y,fmaf(w1.z,xv.z,fmaf(w1.w,xv.w,ax1[s]))));
                ax2[s]=fmaf(w2.x,xv.x,fmaf(w2.y,xv.y,fmaf(w2.z,xv.z,fmaf(w2.w,xv.w,ax2[s]))));
            }
        }
        float ah0[SPB]={0,0,0,0}, ah1[SPB]={0,0,0,0}, ah2[SPB]={0,0,0,0};
        if (!(d[0]&&d[1]&&d[2]&&d[3])) {
            #pragma unroll 4
            for (int cc = 0; cc < H_/4; ++cc) {
                float4 w0=wh0[cc], w1=wh1[cc], w2=wh2[cc];
                #pragma unroll
                for (int s = 0; s < SPB; ++s) if (!d[s]) {
                    float4 hv = ((const float4*)hs[s])[cc];
                    ah0[s]=fmaf(w0.x,hv.x,fmaf(w0.y,hv.y,fmaf(w0.z,hv.z,fmaf(w0.w,hv.w,ah0[s]))));
                    ah1[s]=fmaf(w1.x,hv.x,fmaf(w1.y,hv.y,fmaf(w1.z,hv.z,fmaf(w1.w,hv.w,ah1[s]))));
                    ah2[s]=fmaf(w2.x,hv.x,fmaf(w2.y,hv.y,fmaf(w2.z,hv.z,fmaf(w2.w,hv.w,ah2[s]))));
                }
            }
        }
        float hnew[SPB];
        #pragma unroll
        for (int s = 0; s < SPB; ++s) {
            float hpv = d[s] ? 0.0f : hreg[s];
            float r = sigmoidf_(ax0[s] + bi0 + ah0[s] + bh0);
            float z = sigmoidf_(ax1[s] + bi1 + ah1[s] + bh1);
            float n = tanhf_(ax2[s] + bi2 + r * (ah2[s] + bh2));
            hnew[s] = (1.0f - z) * n + z * hpv;
        }
        __syncthreads();
        #pragma unroll
        for (int s = 0; s < SPB; ++s) {
            hs[s][j] = hnew[s]; hreg[s] = hnew[s];
            out[(size_t)((size_t)t*BN_ + bn0 + s) * H_ + j] = hnew[s];
        }
    }
    #pragma unroll
    for (int s = 0; s < SPB; ++s)
        out[(size_t)T_*BN_*H_ + (size_t)(bn0+s)*H_ + j] = hreg[s];
}

extern "C" void kernel_launch(void* const* d_in, const int* in_sizes, int n_in,
                              void* d_out, int out_size, void* d_ws, size_t ws_size,
                              hipStream_t stream) {
    const float* x     = (const float*)d_in[0];
    const int*   dones = (const int*)  d_in[1];
    const float* h0    = (const float*)d_in[2];
    const float* W_ih  = (const float*)d_in[3];
    const float* W_hh  = (const float*)d_in[4];
    const float* b_ih  = (const float*)d_in[5];
    const float* b_hh  = (const float*)d_in[6];
    float*       out   = (float*)d_out;

    if (ws_size >= WS_NEED) {
        char* ws = (char*)d_ws;
        float*          h1  = (float*)(ws + OFF_H1);
        float*          hin = (float*)(ws + OFF_HIN);
        unsigned short* wbf = (unsigned short*)(ws + OFF_WBF);
        unsigned int*   dmm = (unsigned int*)(ws + OFF_DM);
        unsigned short* xg2 = (unsigned short*)(ws + OFF_XG);

        hipLaunchKernelGGL(xg3_kernel, dim3(256 + 104), dim3(512), 0, stream,
                           x, W_ih, b_ih, b_hh, W_hh, dones, xg2, wbf, dmm);
        hipLaunchKernelGGL(pass1_kernel, dim3((NC_ - 1) * 32), dim3(256), 0, stream,
                           xg2, dmm, wbf, b_hh, h1);
        hipLaunchKernelGGL(pass2_kernel, dim3(BN_), dim3(256), 0, stream,
                           xg2, dmm, wbf, b_hh, h0, h1, hin);
        hipLaunchKernelGGL(pass3_kernel, dim3(NC_ * 32), dim3(256), 0, stream,
                           xg2, dmm, wbf, b_hh, hin, out);
    } else {
        hipLaunchKernelGGL(slotgru_fallback, dim3(BN_ / SPB), dim3(256), 0, stream,
                           x, dones, h0, W_ih, W_hh, b_ih, b_hh, out);
    }
}

// Round 16
// 269.406 us; speedup vs baseline: 1.4366x; 1.0026x over previous
//
#include <hip/hip_runtime.h>
#include <math.h>

#define T_   256
#define B_   32
#define N_   16
#define F_   128
#define H_   256
#define BN_  512          // B*N
#define G3_  768          // 3*H
#define CL_  32           // chunk length
#define NC_  8            // number of chunks (T_/CL_)

typedef __attribute__((ext_vector_type(8))) short  bf16x8;
typedef __attribute__((ext_vector_type(4))) float  f32x4;
typedef __attribute__((ext_vector_type(4))) unsigned short u16x4;

// ---- workspace layout (bytes) ----  (identical to round 6/11)
#define OFF_H1   0ULL                                   // f32 [NC][BN][H]   4 MB
#define OFF_HIN  4194304ULL                             // f32 [NC][BN][H]   4 MB
#define OFF_WBF  8388608ULL                             // bf16 [768][256]   384 KB
#define OFF_DM   8781824ULL                             // u32 [NC][BN]      16 KB
#define OFF_XG   8798208ULL                             // bf16 xg2 tiled    192 MB
#define WS_NEED  210124800ULL

__device__ __forceinline__ unsigned short f2bf(float f) {   // RNE float->bf16
    union { float f; unsigned u; } v; v.f = f;
    unsigned u = v.u + 0x7FFFu + ((v.u >> 16) & 1u);
    return (unsigned short)(u >> 16);
}
__device__ __forceinline__ float bf2f(unsigned short h) {
    union { unsigned u; float f; } v; v.u = ((unsigned)h) << 16;
    return v.f;
}
__device__ __forceinline__ bf16x8 load_pack8(const float* __restrict__ p) {
    f32x4 a = *(const f32x4*)p;
    f32x4 b = *(const f32x4*)(p + 4);
    bf16x8 r;
    r[0]=(short)f2bf(a[0]); r[1]=(short)f2bf(a[1]); r[2]=(short)f2bf(a[2]); r[3]=(short)f2bf(a[3]);
    r[4]=(short)f2bf(b[0]); r[5]=(short)f2bf(b[1]); r[6]=(short)f2bf(b[2]); r[7]=(short)f2bf(b[3]);
    return r;
}

// Fast 1/x via v_rcp_f32 (1 ULP, proven round 15).
__device__ __forceinline__ float fast_rcp(float x) { return __builtin_amdgcn_rcpf(x); }
__device__ __forceinline__ float sigmoidf_(float x) { return fast_rcp(1.0f + __expf(-x)); }
__device__ __forceinline__ float tanhf_(float x)    { return 1.0f - 2.0f * fast_rcp(__expf(2.0f * x) + 1.0f); }

// Pin a bf16x8 fragment to the AGPR class (empty asm; builtin MFMA reads A
// from AGPR directly — AV operand class — with compiler-managed hazards).
__device__ __forceinline__ bf16x8 pin_a(bf16x8 v) {
    bf16x8 r;
    asm("" : "=a"(r) : "0"(v));
    return r;
}

// xg2 tiled layout: u16 index for element (tt, seq, g)
__device__ __forceinline__ size_t xg2_idx(int tt, int seq, int g) {
    return ((((size_t)tt * 32 + (seq >> 4)) * 48 + (g >> 4)) * 64
            + ((g >> 2) & 3) * 16 + (seq & 15)) * 4 + (g & 3);
}

// ---------------------------------------------------------------------------
// xg3: pipelined input-projection GEMM (round-11 proven, ~90 us; write-BW
// bound). 256 persistent compute blocks (1/CU, 512 thr), double-buffered LDS.
// ---------------------------------------------------------------------------
__global__ __launch_bounds__(512, 2)
void xg3_kernel(const float* __restrict__ x, const float* __restrict__ W_ih,
                const float* __restrict__ b_ih, const float* __restrict__ b_hh,
                const float* __restrict__ W_hh, const int* __restrict__ dones,
                unsigned short* __restrict__ xg2,
                unsigned short* __restrict__ wbf, unsigned int* __restrict__ dm)
{
    const int tid = threadIdx.x;
    if (blockIdx.x >= 256) {                        // ---- fused prep ----
        const int bid2 = blockIdx.x - 256;
        if (bid2 < 96) {                            // W_hh f32 -> bf16
            const int i4 = bid2 * 512 + tid;        // 49152 f32x4 units
            f32x4 w = ((const f32x4*)W_hh)[i4];
            u16x4 o;
            #pragma unroll
            for (int q = 0; q < 4; ++q) o[q] = f2bf(w[q]);
            ((u16x4*)wbf)[i4] = o;
        } else {                                    // done masks (u32, CL=32)
            const int u = (bid2 - 96) * 512 + tid;  // 4096 = NC*BN
            const int c = u >> 9, s = u & 511;
            unsigned m = 0;
            #pragma unroll
            for (int k = 0; k < CL_; ++k)
                m |= (dones[(c * CL_ + k) * BN_ + s] ? 1u : 0u) << k;
            dm[c * BN_ + s] = m;
        }
        return;
    }

    __shared__ __align__(16) unsigned short xls[2][128][136];   // 69.6 KB dbuf

    const int wave = tid >> 6, lane = tid & 63;
    const int lr = lane & 15, lg = lane >> 4;
    const int t  = blockIdx.x;                      // one timestep per block
    const int g0 = wave * 96;

    bf16x8 wf[6][4];
    #pragma unroll
    for (int gt = 0; gt < 6; ++gt)
        #pragma unroll
        for (int kt = 0; kt < 4; ++kt)
            wf[gt][kt] = load_pack8(W_ih + (size_t)(g0 + gt*16 + lr) * F_ + kt*32 + lg*8);

    float bv[6][4];
    #pragma unroll
    for (int gt = 0; gt < 6; ++gt)
        #pragma unroll
        for (int q = 0; q < 4; ++q) {
            const int g = g0 + gt*16 + lg*4 + q;
            bv[gt][q] = b_ih[g] + (g < 2*H_ ? b_hh[g] : 0.0f);
        }

    {
        f32x4 sv0[8];
        #pragma unroll
        for (int s = 0; s < 8; ++s)
            sv0[s] = ((const f32x4*)x)[(size_t)t * 16384 + s*512 + tid];
        #pragma unroll
        for (int s = 0; s < 8; ++s) {
            u16x4 o;
            #pragma unroll
            for (int q = 0; q < 4; ++q) o[q] = f2bf(sv0[s][q]);
            const int u = s*512 + tid;
            *(u16x4*)&xls[0][u >> 5][(u & 31) * 4] = o;
        }
    }
    __syncthreads();

    int buf = 0;
    #pragma unroll 1
    for (int i = 0; i < 4; ++i) {
        f32x4 sv[8];
        if (i < 3) {
            #pragma unroll
            for (int s = 0; s < 8; ++s)
                sv[s] = ((const f32x4*)x)[(size_t)t * 16384 + (i+1)*4096 + s*512 + tid];
        }

        #pragma unroll
        for (int tbt = 0; tbt < 8; ++tbt) {
            bf16x8 xf[4];
            #pragma unroll
            for (int kt = 0; kt < 4; ++kt)
                xf[kt] = *(const bf16x8*)&xls[buf][tbt*16 + lr][kt*32 + lg*8];

            f32x4 acc[6];
            #pragma unroll
            for (int gt = 0; gt < 6; ++gt) acc[gt] = (f32x4){0.f, 0.f, 0.f, 0.f};

            #pragma unroll
            for (int kt = 0; kt < 4; ++kt)
                #pragma unroll
                for (int gt = 0; gt < 6; ++gt)
                    acc[gt] = __builtin_amdgcn_mfma_f32_16x16x32_bf16(wf[gt][kt], xf[kt], acc[gt], 0, 0, 0);

            const int sbg = i*8 + tbt;
            #pragma unroll
            for (int gt = 0; gt < 6; ++gt) {
                u16x4 o;
                #pragma unroll
                for (int q = 0; q < 4; ++q) o[q] = f2bf(acc[gt][q] + bv[gt][q]);
                const size_t base = (((size_t)t * 32 + sbg) * 48 + (wave*6 + gt)) * 64 + lane;
                *(u16x4*)(xg2 + base * 4) = o;
            }
        }

        if (i < 3) {
            #pragma unroll
            for (int s = 0; s < 8; ++s) {
                u16x4 o;
                #pragma unroll
                for (int q = 0; q < 4; ++q) o[q] = f2bf(sv[s][q]);
                const int u = s*512 + tid;
                *(u16x4*)&xls[buf ^ 1][u >> 5][(u & 31) * 4] = o;
            }
            __syncthreads();
        }
        buf ^= 1;
    }
}

// ---------------------------------------------------------------------------
// pass1 (round-15 verbatim): 256 thr = 4 waves, 1 block/CU.
// ---------------------------------------------------------------------------
__global__ __launch_bounds__(256, 1)
void pass1_kernel(const unsigned short* __restrict__ xg2,
                  const unsigned int*  __restrict__ dm,
                  const unsigned short* __restrict__ wbf,
                  const float* __restrict__ b_hh,
                  float* __restrict__ h1)
{
    __shared__ __align__(16) unsigned short hT[2][8][4][16][8];   // 16 KB
    __shared__ __align__(16) float hpL[16][260];                  // 16.6 KB
    __shared__ float bhnL[H_];                                    // 1 KB

    const int tid  = threadIdx.x;
    const int wave = tid >> 6, lane = tid & 63;
    const int lr = lane & 15, lg = lane >> 4;
    const int c   = blockIdx.x >> 5;            // 0..NC_-2
    const int bn0 = (blockIdx.x & 31) * 16;
    const int jb  = wave * 64;

    const unsigned m = dm[c * BN_ + bn0 + lr];
    if (__ballot(m != 0) == 0ULL) return;       // uniform across waves

    int last = m ? (31 - __builtin_clz(m)) : 31;
    #pragma unroll
    for (int w = 1; w < 16; w <<= 1) last = min(last, __shfl_xor(last, w));

    bhnL[tid] = b_hh[2*H_ + tid];
    #pragma unroll
    for (int sweep = 0; sweep < 2; ++sweep)
        ((bf16x8*)hT)[sweep * 256 + tid] = (bf16x8)(short)0;
    #pragma unroll
    for (int sweep = 0; sweep < 4; ++sweep) {
        const int u = sweep * 256 + tid, seq = u >> 6, jq = u & 63;
        *(f32x4*)&hpL[seq][jq * 4] = (f32x4){0.f, 0.f, 0.f, 0.f};
    }

    bf16x8 wfa[8][8];   // r+z -> AGPR
    bf16x8 wfv[4][8];   // n   -> VGPR
    #pragma unroll
    for (int mt = 0; mt < 8; ++mt) {
        const int row = (mt >> 2) * H_ + jb + (mt & 3) * 16 + lr;
        #pragma unroll
        for (int kt = 0; kt < 8; ++kt)
            wfa[mt][kt] = pin_a(*(const bf16x8*)(wbf + (size_t)row * H_ + kt*32 + lg*8));
    }
    #pragma unroll
    for (int ms = 0; ms < 4; ++ms) {
        const int row = 2 * H_ + jb + ms * 16 + lr;
        #pragma unroll
        for (int kt = 0; kt < 8; ++kt)
            wfv[ms][kt] = *(const bf16x8*)(wbf + (size_t)row * H_ + kt*32 + lg*8);
    }
    __syncthreads();

    const f32x4 zero4 = (f32x4){0.f, 0.f, 0.f, 0.f};    // loop-invariant C-seed
    const int sb = bn0 >> 4;
    int buf = 0;
    for (int t = last; t < CL_; ++t) {
        const int tt = c * CL_ + t;
        const int tb = (tt * 32 + sb) * 48;

        u16x4 xv[3][4];
        #pragma unroll
        for (int g = 0; g < 3; ++g)
            #pragma unroll
            for (int ms = 0; ms < 4; ++ms)
                xv[g][ms] = ((const u16x4*)xg2)[(size_t)(tb + g*16 + wave*4 + ms) * 64 + lane];

        const int d = (m >> t) & 1;
        const short dms = (short)(d ? 0 : -1);

        f32x4 acc[12];
        // first k-tile seeds acc directly (r/z from zero4, n from bias)
        {
            bf16x8 hv = *(const bf16x8*)&hT[buf][0][lg][lr][0];
            hv = hv & dms;
            #pragma unroll
            for (int mt = 0; mt < 8; ++mt)
                acc[mt] = __builtin_amdgcn_mfma_f32_16x16x32_bf16(wfa[mt][0], hv, zero4, 0, 0, 0);
            #pragma unroll
            for (int ms = 0; ms < 4; ++ms)
                acc[8 + ms] = __builtin_amdgcn_mfma_f32_16x16x32_bf16(
                    wfv[ms][0], hv, *(const f32x4*)&bhnL[jb + ms*16 + lg*4], 0, 0, 0);
        }
        #pragma unroll
        for (int kt = 1; kt < 8; ++kt) {
            bf16x8 hv = *(const bf16x8*)&hT[buf][kt][lg][lr][0];
            hv = hv & dms;
            #pragma unroll
            for (int mt = 0; mt < 8; ++mt)
                acc[mt] = __builtin_amdgcn_mfma_f32_16x16x32_bf16(wfa[mt][kt], hv, acc[mt], 0, 0, 0);
            #pragma unroll
            for (int ms = 0; ms < 4; ++ms)
                acc[8 + ms] = __builtin_amdgcn_mfma_f32_16x16x32_bf16(wfv[ms][kt], hv, acc[8 + ms], 0, 0, 0);
        }

        #pragma unroll
        for (int ms = 0; ms < 4; ++ms) {
            const int jq = jb + ms*16 + lg*4;
            f32x4 hp4 = *(const f32x4*)&hpL[lr][jq];
            f32x4 hnew4; u16x4 hb;
            #pragma unroll
            for (int q = 0; q < 4; ++q) {
                float r = sigmoidf_(acc[0 + ms][q] + bf2f(xv[0][ms][q]));
                float z = sigmoidf_(acc[4 + ms][q] + bf2f(xv[1][ms][q]));
                float n = tanhf_(bf2f(xv[2][ms][q]) + r * acc[8 + ms][q]);
                float hpv = d ? 0.0f : hp4[q];
                float hn2 = n + z * (hpv - n);
                hnew4[q] = hn2; hb[q] = f2bf(hn2);
            }
            *(f32x4*)&hpL[lr][jq] = hnew4;
            *(u16x4*)&hT[buf ^ 1][jq >> 5][(jq >> 3) & 3][lr][jq & 7] = hb;
        }
        __syncthreads();
        buf ^= 1;
    }

    #pragma unroll
    for (int ms = 0; ms < 4; ++ms) {
        const int jq = jb + ms*16 + lg*4;
        f32x4 hv = *(const f32x4*)&hpL[lr][jq];
        *(f32x4*)(h1 + ((size_t)c * BN_ + bn0 + lr) * H_ + jq) = hv;
    }
}

// ---------------------------------------------------------------------------
// pass2: chain h across chunks. Copy when chunk has a done; rare VALU GRU.
// ---------------------------------------------------------------------------
__global__ __launch_bounds__(256)
void pass2_kernel(const unsigned short* __restrict__ xg2,
                  const unsigned int*  __restrict__ dm,
                  const unsigned short* __restrict__ wbf,
                  const float* __restrict__ b_hh,
                  const float* __restrict__ h0,
                  const float* __restrict__ h1,
                  float* __restrict__ hin)
{
    __shared__ unsigned short hsb[H_];
    const int s = blockIdx.x, j = threadIdx.x;
    float h = h0[(size_t)s * H_ + j];
    const float bhn = b_hh[2*H_ + j];

    for (int c = 0; c < NC_; ++c) {
        hin[((size_t)c * BN_ + s) * H_ + j] = h;
        if (c == NC_ - 1) break;
        const unsigned m = dm[c * BN_ + s];         // block-uniform
        if (m) {
            h = h1[((size_t)c * BN_ + s) * H_ + j];
        } else {
            for (int t = 0; t < CL_; ++t) {
                hsb[j] = f2bf(h);
                __syncthreads();
                float a0 = 0.f, a1 = 0.f, a2 = 0.f;
                for (int k = 0; k < H_; ++k) {
                    float hk = bf2f(hsb[k]);
                    a0 = fmaf(bf2f(wbf[(size_t)j * H_ + k]),          hk, a0);
                    a1 = fmaf(bf2f(wbf[(size_t)(H_ + j) * H_ + k]),   hk, a1);
                    a2 = fmaf(bf2f(wbf[(size_t)(2*H_ + j) * H_ + k]), hk, a2);
                }
                const int tt = c * CL_ + t;
                float xr = bf2f(xg2[xg2_idx(tt, s, j)]);
                float xz = bf2f(xg2[xg2_idx(tt, s, H_ + j)]);
                float xn = bf2f(xg2[xg2_idx(tt, s, 2*H_ + j)]);
                float r = sigmoidf_(a0 + xr);
                float z = sigmoidf_(a1 + xz);
                float n = tanhf_(xn + r * (a2 + bhn));
                h = n + z * (h - n);
                __syncthreads();
            }
        }
    }
}

// ---------------------------------------------------------------------------
// pass3: round-15 core + deferred out-stores. Epilogue writes only LDS
// (hpL holds h_new); AFTER the barrier, re-read hpL and issue the global
// stores — they drain at the NEXT barrier, a full step later. Zero-register
// change (no values live across the barrier).
// ---------------------------------------------------------------------------
__global__ __launch_bounds__(256, 1)
void pass3_kernel(const unsigned short* __restrict__ xg2,
                  const unsigned int*  __restrict__ dm,
                  const unsigned short* __restrict__ wbf,
                  const float* __restrict__ b_hh,
                  const float* __restrict__ hin,
                  float* __restrict__ out)
{
    __shared__ __align__(16) unsigned short hT[2][8][4][16][8];   // 16 KB
    __shared__ __align__(16) float hpL[16][260];                  // 16.6 KB
    __shared__ float bhnL[H_];                                    // 1 KB

    const int tid  = threadIdx.x;
    const int wave = tid >> 6, lane = tid & 63;
    const int lr = lane & 15, lg = lane >> 4;
    const int c   = blockIdx.x >> 5;            // 0..NC_-1
    const int bn0 = (blockIdx.x & 31) * 16;
    const int jb  = wave * 64;

    const unsigned m = dm[c * BN_ + bn0 + lr];

    bhnL[tid] = b_hh[2*H_ + tid];
    // stage h_in: f32 -> hpL, bf16 -> hT[0]
    #pragma unroll
    for (int sweep = 0; sweep < 4; ++sweep) {
        const int u = sweep * 256 + tid, seq = u >> 6, jq = u & 63;
        f32x4 hv = ((const f32x4*)hin)[((size_t)c * BN_ + bn0 + seq) * 64 + jq];
        *(f32x4*)&hpL[seq][jq * 4] = hv;
    }
    #pragma unroll
    for (int sweep = 0; sweep < 2; ++sweep) {
        const int u = sweep * 256 + tid, col = u & 15, kb = (u >> 4) * 8;
        bf16x8 hv = load_pack8(hin + ((size_t)c * BN_ + bn0 + col) * H_ + kb);
        ((bf16x8*)hT)[u] = hv;
    }

    bf16x8 wfa[8][8];
    bf16x8 wfv[4][8];
    #pragma unroll
    for (int mt = 0; mt < 8; ++mt) {
        const int row = (mt >> 2) * H_ + jb + (mt & 3) * 16 + lr;
        #pragma unroll
        for (int kt = 0; kt < 8; ++kt)
            wfa[mt][kt] = pin_a(*(const bf16x8*)(wbf + (size_t)row * H_ + kt*32 + lg*8));
    }
    #pragma unroll
    for (int ms = 0; ms < 4; ++ms) {
        const int row = 2 * H_ + jb + ms * 16 + lr;
        #pragma unroll
        for (int kt = 0; kt < 8; ++kt)
            wfv[ms][kt] = *(const bf16x8*)(wbf + (size_t)row * H_ + kt*32 + lg*8);
    }
    __syncthreads();

    const f32x4 zero4 = (f32x4){0.f, 0.f, 0.f, 0.f};    // loop-invariant C-seed
    const int sb = bn0 >> 4;
    int buf = 0;
    for (int t = 0; t < CL_; ++t) {
        const int tt = c * CL_ + t;
        const int tb = (tt * 32 + sb) * 48;

        u16x4 xv[3][4];
        #pragma unroll
        for (int g = 0; g < 3; ++g)
            #pragma unroll
            for (int ms = 0; ms < 4; ++ms)
                xv[g][ms] = ((const u16x4*)xg2)[(size_t)(tb + g*16 + wave*4 + ms) * 64 + lane];

        const int d = (m >> t) & 1;
        const short dms = (short)(d ? 0 : -1);

        f32x4 acc[12];
        {
            bf16x8 hv = *(const bf16x8*)&hT[buf][0][lg][lr][0];
            hv = hv & dms;
            #pragma unroll
            for (int mt = 0; mt < 8; ++mt)
                acc[mt] = __builtin_amdgcn_mfma_f32_16x16x32_bf16(wfa[mt][0], hv, zero4, 0, 0, 0);
            #pragma unroll
            for (int ms = 0; ms < 4; ++ms)
                acc[8 + ms] = __builtin_amdgcn_mfma_f32_16x16x32_bf16(
                    wfv[ms][0], hv, *(const f32x4*)&bhnL[jb + ms*16 + lg*4], 0, 0, 0);
        }
        #pragma unroll
        for (int kt = 1; kt < 8; ++kt) {
            bf16x8 hv = *(const bf16x8*)&hT[buf][kt][lg][lr][0];
            hv = hv & dms;
            #pragma unroll
            for (int mt = 0; mt < 8; ++mt)
                acc[mt] = __builtin_amdgcn_mfma_f32_16x16x32_bf16(wfa[mt][kt], hv, acc[mt], 0, 0, 0);
            #pragma unroll
            for (int ms = 0; ms < 4; ++ms)
                acc[8 + ms] = __builtin_amdgcn_mfma_f32_16x16x32_bf16(wfv[ms][kt], hv, acc[8 + ms], 0, 0, 0);
        }

        #pragma unroll
        for (int ms = 0; ms < 4; ++ms) {
            const int jq = jb + ms*16 + lg*4;
            f32x4 hp4 = *(const f32x4*)&hpL[lr][jq];
            f32x4 hnew4; u16x4 hb;
            #pragma unroll
            for (int q = 0; q < 4; ++q) {
                float r = sigmoidf_(acc[0 + ms][q] + bf2f(xv[0][ms][q]));
                float z = sigmoidf_(acc[4 + ms][q] + bf2f(xv[1][ms][q]));
                float n = tanhf_(bf2f(xv[2][ms][q]) + r * acc[8 + ms][q]);
                float hpv = d ? 0.0f : hp4[q];
                float hn2 = n + z * (hpv - n);
                hnew4[q] = hn2; hb[q] = f2bf(hn2);
            }
            *(f32x4*)&hpL[lr][jq] = hnew4;                       // LDS only
            *(u16x4*)&hT[buf ^ 1][jq >> 5][(jq >> 3) & 3][lr][jq & 7] = hb;
        }
        __syncthreads();        // drains ds + previous step's out-stores

        // deferred out-stores: re-read hpL (holds this step's h), issue
        // global stores; they retire under the NEXT step's work.
        #pragma unroll
        for (int ms = 0; ms < 4; ++ms) {
            const int jq = jb + ms*16 + lg*4;
            f32x4 hv = *(const f32x4*)&hpL[lr][jq];
            *(f32x4*)(out + ((size_t)tt * BN_ + bn0 + lr) * H_ + jq) = hv;
        }
        buf ^= 1;
    }

    if (c == NC_ - 1) {
        #pragma unroll
        for (int ms = 0; ms < 4; ++ms) {
            const int jq = jb + ms*16 + lg*4;
            f32x4 hv = *(const f32x4*)&hpL[lr][jq];
            *(f32x4*)(out + (size_t)T_ * BN_ * H_ + (size_t)(bn0 + lr) * H_ + jq) = hv;
        }
    }
}

// ---------------------------------------------------------------------------
// Fallback (ws too small): fp32 VALU persistent kernel (correct, slow)
// ---------------------------------------------------------------------------
#define SPB 4
__global__ __launch_bounds__(256, 1)
void slotgru_fallback(const float* __restrict__ x, const int* __restrict__ dones,
                      const float* __restrict__ h0, const float* __restrict__ W_ih,
                      const float* __restrict__ W_hh, const float* __restrict__ b_ih,
                      const float* __restrict__ b_hh, float* __restrict__ out)
{
    __shared__ __align__(16) float xs[SPB][F_];
    __shared__ __align__(16) float hs[SPB][H_];
    const int j = threadIdx.x, bn0 = blockIdx.x * SPB;
    const float bi0 = b_ih[j], bi1 = b_ih[H_ + j], bi2 = b_ih[2*H_ + j];
    const float bh0 = b_hh[j], bh1 = b_hh[H_ + j], bh2 = b_hh[2*H_ + j];
    const float4* wi0 = (const float4*)(W_ih + (size_t)j * F_);
    const float4* wi1 = (const float4*)(W_ih + (size_t)(H_ + j) * F_);
    const float4* wi2 = (const float4*)(W_ih + (size_t)(2*H_ + j) * F_);
    const float4* wh0 = (const float4*)(W_hh + (size_t)j * H_);
    const float4* wh1 = (const float4*)(W_hh + (size_t)(H_ + j) * H_);
    const float4* wh2 = (const float4*)(W_hh + (size_t)(2*H_ + j) * H_);
    float hreg[SPB];
    #pragma unroll
    for (int s = 0; s < SPB; ++s) { float h = h0[(size_t)(bn0+s)*H_ + j]; hreg[s]=h; hs[s][j]=h; }
    for (int t = 0; t < T_; ++t) {
        int d[SPB];
        #pragma unroll
        for (int s = 0; s < SPB; ++s) d[s] = dones[(size_t)t*BN_ + bn0 + s];
        const float* xsrc = x + (size_t)((size_t)t*BN_ + bn0) * F_;
        ((float*)xs)[j] = xsrc[j]; ((float*)xs)[j+256] = xsrc[j+256];
        #pragma unroll
        for (int s = 0; s < SPB; ++s) if (d[s]) hs[s][j] = 0.0f;
        __syncthreads();
        float ax0[SPB]={0,0,0,0}, ax1[SPB]={0,0,0,0}, ax2[SPB]={0,0,0,0};
        #pragma unroll 8
        for (int cc = 0; cc < F_/4; ++cc) {
            float4 w0=wi0[cc], w1=wi1[cc], w2=wi2[cc];
            #pragma unroll
            for (int s = 0; s < SPB; ++s) {
                float4 xv = ((const float4*)xs[s])[cc];
                ax0[s]=fmaf(w0.x,xv.x,fmaf(w0.y,xv.y,fmaf(w0.z,xv.z,fmaf(w0.w,xv.w,ax0[s]))));
                ax1[s]=fmaf(w1.x,xv.x,fmaf(w1.y,xv.y,fmaf(w1.z,xv.z,fmaf(w1.w,xv.w,ax1[s]))));
                ax2[s]=fmaf(w2.x,xv.x,fmaf(w2.y,xv.y,fmaf(w2.z,xv.z,fmaf(w2.w,xv.w,ax2[s]))));
            }
        }
        float ah0[SPB]={0,0,0,0}, ah1[SPB]={0,0,0,0}, ah2[SPB]={0,0,0,0};
        if (!(d[0]&&d[1]&&d[2]&&d[3])) {
            #pragma unroll 4
            for (int cc = 0; cc < H_/4; ++cc) {
                float4 w0=wh0[cc], w1=wh1[cc], w2=wh2[cc];
                #pragma unroll
                for (int s = 0; s < SPB; ++s) if (!d[s]) {
                    float4 hv = ((const float4*)hs[s])[cc];
                    ah0[s]=fmaf(w0.x,hv.x,fmaf(w0.y,hv.y,fmaf(w0.z,hv.z,fmaf(w0.w,hv.w,ah0[s]))));
                    ah1[s]=fmaf(w1.x,hv.x,fmaf(w1.y,hv.y,fmaf(w1.z,hv.z,fmaf(w1.w,hv.w,ah1[s]))));
                    ah2[s]=fmaf(w2.x,hv.x,fmaf(w2.y,hv.y,fmaf(w2.z,hv.z,fmaf(w2.w,hv.w,ah2[s]))));
                }
            }
        }
        float hnew[SPB];
        #pragma unroll
        for (int s = 0; s < SPB; ++s) {
            float hpv = d[s] ? 0.0f : hreg[s];
            float r = sigmoidf_(ax0[s] + bi0 + ah0[s] + bh0);
            float z = sigmoidf_(ax1[s] + bi1 + ah1[s] + bh1);
            float n = tanhf_(ax2[s] + bi2 + r * (ah2[s] + bh2));
            hnew[s] = (1.0f - z) * n + z * hpv;
        }
        __syncthreads();
        #pragma unroll
        for (int s = 0; s < SPB; ++s) {
            hs[s][j] = hnew[s]; hreg[s] = hnew[s];
            out[(size_t)((size_t)t*BN_ + bn0 + s) * H_ + j] = hnew[s];
        }
    }
    #pragma unroll
    for (int s = 0; s < SPB; ++s)
        out[(size_t)T_*BN_*H_ + (size_t)(bn0+s)*H_ + j] = hreg[s];
}

extern "C" void kernel_launch(void* const* d_in, const int* in_sizes, int n_in,
                              void* d_out, int out_size, void* d_ws, size_t ws_size,
                              hipStream_t stream) {
    const float* x     = (const float*)d_in[0];
    const int*   dones = (const int*)  d_in[1];
    const float* h0    = (const float*)d_in[2];
    const float* W_ih  = (const float*)d_in[3];
    const float* W_hh  = (const float*)d_in[4];
    const float* b_ih  = (const float*)d_in[5];
    const float* b_hh  = (const float*)d_in[6];
    float*       out   = (float*)d_out;

    if (ws_size >= WS_NEED) {
        char* ws = (char*)d_ws;
        float*          h1  = (float*)(ws + OFF_H1);
        float*          hin = (float*)(ws + OFF_HIN);
        unsigned short* wbf = (unsigned short*)(ws + OFF_WBF);
        unsigned int*   dmm = (unsigned int*)(ws + OFF_DM);
        unsigned short* xg2 = (unsigned short*)(ws + OFF_XG);

        hipLaunchKernelGGL(xg3_kernel, dim3(256 + 104), dim3(512), 0, stream,
                           x, W_ih, b_ih, b_hh, W_hh, dones, xg2, wbf, dmm);
        hipLaunchKernelGGL(pass1_kernel, dim3((NC_ - 1) * 32), dim3(256), 0, stream,
                           xg2, dmm, wbf, b_hh, h1);
        hipLaunchKernelGGL(pass2_kernel, dim3(BN_), dim3(256), 0, stream,
                           xg2, dmm, wbf, b_hh, h0, h1, hin);
        hipLaunchKernelGGL(pass3_kernel, dim3(NC_ * 32), dim3(256), 0, stream,
                           xg2, dmm, wbf, b_hh, hin, out);
    } else {
        hipLaunchKernelGGL(slotgru_fallback, dim3(BN_ / SPB), dim3(256), 0, stream,
                           x, dones, h0, W_ih, W_hh, b_ih, b_hh, out);
    }
}